// Round 1
// baseline (1754.783 us; speedup 1.0000x reference)
//
#include <hip/hip_runtime.h>

// PerformerAttnBlock on MI355X — Round 0: correct fp32 baseline.
// B=4, IN=512, T=4096, EMBED=1024, H=16, D=64, F=256.
// Workspace layout (floats): Q[16384*1024] K[16384*1024] V/attn[16384*1024]
//                            KV[4*16*256*64] Ksum[4*16*256]   (~218 MB total)

constexpr int kB  = 4;
constexpr int kIn = 512;
constexpr int kT  = 4096;
constexpr int kE  = 1024;
constexpr int kH  = 16;
constexpr int kD  = 64;
constexpr int kF  = 256;

// ---------------------------------------------------------------- zero
__global__ __launch_bounds__(256) void zero_kernel(float* __restrict__ p, int n) {
    int i = blockIdx.x * 256 + threadIdx.x;
    if (i < n) p[i] = 0.f;
}

// ---------------------------------------------------------------- copy x -> out[:, :512, :]
// out is (B, 1536, T); first 512 channels of each batch are x[b] verbatim.
__global__ __launch_bounds__(256) void copy_x_kernel(const float* __restrict__ x,
                                                     float* __restrict__ out) {
    const int perB4 = kIn * kT / 4;          // 524288 float4 per batch
    int idx = blockIdx.x * 256 + threadIdx.x;
    if (idx < kB * perB4) {
        int b = idx / perB4, e = idx % perB4;
        ((float4*)out)[(size_t)b * ((kIn + kE) * kT / 4) + e] = ((const float4*)x)[idx];
    }
}

// ---------------------------------------------------------------- GEMM: C[m][n] = sum_k x[b,k,t]*W[k][n]
// m = b*T + t (A is effectively column-major: t contiguous in global). 128x128x8 tile.
__global__ __launch_bounds__(256) void gemm_xw_kernel(const float* __restrict__ x,
                                                      const float* __restrict__ W,
                                                      float* __restrict__ C) {
    __shared__ float As[8][132];   // [k][m]
    __shared__ float Bs[8][132];   // [k][n]
    const int tid = threadIdx.x;
    const int tx = tid & 15, ty = tid >> 4;
    const int n0 = blockIdx.x * 128;
    const int m0 = blockIdx.y * 128;
    const int b  = m0 >> 12;               // T=4096 divisible by 128: tiles never cross b
    const int t0 = m0 & 4095;
    const float* xb = x + (size_t)b * kIn * kT;
    const int lk = tid >> 5;               // 0..7
    const int lm = (tid & 31) << 2;        // 0..124
    float c[8][8] = {};
    for (int k0 = 0; k0 < kIn; k0 += 8) {
        float4 a4 = *(const float4*)(xb + (size_t)(k0 + lk) * kT + t0 + lm);
        float4 b4 = *(const float4*)(W + (size_t)(k0 + lk) * kE + n0 + lm);
        __syncthreads();
        *(float4*)&As[lk][lm] = a4;
        *(float4*)&Bs[lk][lm] = b4;
        __syncthreads();
#pragma unroll
        for (int kk = 0; kk < 8; ++kk) {
            float a[8], bb[8];
            *(float4*)&a[0]  = *(float4*)&As[kk][ty * 8];
            *(float4*)&a[4]  = *(float4*)&As[kk][ty * 8 + 4];
            *(float4*)&bb[0] = *(float4*)&Bs[kk][tx * 8];
            *(float4*)&bb[4] = *(float4*)&Bs[kk][tx * 8 + 4];
#pragma unroll
            for (int i = 0; i < 8; ++i)
#pragma unroll
                for (int j = 0; j < 8; ++j) c[i][j] = fmaf(a[i], bb[j], c[i][j]);
        }
    }
#pragma unroll
    for (int i = 0; i < 8; ++i) {
        float* p = C + (size_t)(m0 + ty * 8 + i) * kE + n0 + tx * 8;
        *(float4*)p       = make_float4(c[i][0], c[i][1], c[i][2], c[i][3]);
        *(float4*)(p + 4) = make_float4(c[i][4], c[i][5], c[i][6], c[i][7]);
    }
}

// ---------------------------------------------------------------- GEMM: out2 = attn @ Wo, store transposed
// A row-major (16384 x 1024); epilogue writes out[b, 512+n, t].
__global__ __launch_bounds__(256) void gemm_ao_kernel(const float* __restrict__ A,
                                                      const float* __restrict__ W,
                                                      float* __restrict__ out) {
    __shared__ float As[8][132];
    __shared__ float Bs[8][132];
    const int tid = threadIdx.x;
    const int tx = tid & 15, ty = tid >> 4;
    const int n0 = blockIdx.x * 128;
    const int m0 = blockIdx.y * 128;
    const int lk = tid >> 5;
    const int lm = (tid & 31) << 2;
    const int am = tid >> 1;               // 0..127
    const int ah = (tid & 1) << 2;         // 0 or 4
    float c[8][8] = {};
    for (int k0 = 0; k0 < kE; k0 += 8) {
        float4 a4 = *(const float4*)(A + (size_t)(m0 + am) * kE + k0 + ah);
        float4 b4 = *(const float4*)(W + (size_t)(k0 + lk) * kE + n0 + lm);
        __syncthreads();
        As[ah + 0][am] = a4.x; As[ah + 1][am] = a4.y;
        As[ah + 2][am] = a4.z; As[ah + 3][am] = a4.w;
        *(float4*)&Bs[lk][lm] = b4;
        __syncthreads();
#pragma unroll
        for (int kk = 0; kk < 8; ++kk) {
            float a[8], bb[8];
            *(float4*)&a[0]  = *(float4*)&As[kk][ty * 8];
            *(float4*)&a[4]  = *(float4*)&As[kk][ty * 8 + 4];
            *(float4*)&bb[0] = *(float4*)&Bs[kk][tx * 8];
            *(float4*)&bb[4] = *(float4*)&Bs[kk][tx * 8 + 4];
#pragma unroll
            for (int i = 0; i < 8; ++i)
#pragma unroll
                for (int j = 0; j < 8; ++j) c[i][j] = fmaf(a[i], bb[j], c[i][j]);
        }
    }
    const int b = m0 >> 12, t0 = m0 & 4095;
    float* ob = out + (size_t)b * (kIn + kE) * kT;
#pragma unroll
    for (int j = 0; j < 8; ++j) {
        float* p = ob + (size_t)(kIn + n0 + tx * 8 + j) * kT + t0 + ty * 8;
        *(float4*)p       = make_float4(c[0][j], c[1][j], c[2][j], c[3][j]);
        *(float4*)(p + 4) = make_float4(c[4][j], c[5][j], c[6][j], c[7][j]);
    }
}

// ---------------------------------------------------------------- Phase A: KV[b,h,f,d] and Ksum[b,h,f]
// Per block: one (b,h), 512 timesteps (8 x 64-tiles). Kp = exp(K.proj^T)+eps computed tile-wise
// in LDS, then KV += Kp^T.V via register-tiled GEMM; fp32 atomics combine 8 T-groups.
__global__ __launch_bounds__(256) void phaseA_kernel(const float* __restrict__ Kg,
                                                     const float* __restrict__ Vg,
                                                     const float* __restrict__ proj,
                                                     float* __restrict__ KVg,
                                                     float* __restrict__ Ksumg) {
    __shared__ float Ksd[64][68];   // [d][t]
    __shared__ float Vs[64][68];    // [t][d]
    __shared__ float Pjd[64][68];   // [d][f]   (per 64-f chunk)
    __shared__ float Kps[64][68];   // [t][f]
    const int tid = threadIdx.x;
    const int tx = tid & 15, ty = tid >> 4;
    const int bh = blockIdx.x;
    const int b = bh >> 4, h = bh & 15;
    const int grp = blockIdx.y;     // 0..7 T-split
    const int myfc = tid >> 6, lane = tid & 63;

    float kv[4][4][4];
#pragma unroll
    for (int fc = 0; fc < 4; ++fc)
#pragma unroll
        for (int i = 0; i < 4; ++i)
#pragma unroll
            for (int j = 0; j < 4; ++j) kv[fc][i][j] = 0.f;
    float ksum_acc = 0.f;

    for (int it = 0; it < 8; ++it) {
        const int t0 = grp * 512 + it * 64;
        __syncthreads();   // prior iter done reading Ksd/Vs
#pragma unroll
        for (int r = 0; r < 4; ++r) {
            int lin = r * 256 + tid;
            int t = lin >> 4;
            int d4 = (lin & 15) << 2;
            size_t goff = (size_t)(b * kT + t0 + t) * kE + h * kD + d4;
            float4 k4 = *(const float4*)(Kg + goff);
            Ksd[d4 + 0][t] = k4.x; Ksd[d4 + 1][t] = k4.y;
            Ksd[d4 + 2][t] = k4.z; Ksd[d4 + 3][t] = k4.w;
            *(float4*)&Vs[t][d4] = *(const float4*)(Vg + goff);
        }
#pragma unroll
        for (int fc = 0; fc < 4; ++fc) {
            __syncthreads();  // K/V staged; prior fc done reading Pjd/Kps
#pragma unroll
            for (int r = 0; r < 4; ++r) {
                int lin = r * 256 + tid;
                int f = lin >> 4;
                int d4 = (lin & 15) << 2;
                float4 p4 = *(const float4*)(proj + (size_t)(fc * 64 + f) * kD + d4);
                Pjd[d4 + 0][f] = p4.x; Pjd[d4 + 1][f] = p4.y;
                Pjd[d4 + 2][f] = p4.z; Pjd[d4 + 3][f] = p4.w;
            }
            __syncthreads();
            // S[t][f] = sum_d K[t][d] * proj[f][d]
            float s[4][4] = {};
#pragma unroll 8
            for (int d = 0; d < 64; ++d) {
                float4 a = *(float4*)&Ksd[d][ty * 4];
                float4 p = *(float4*)&Pjd[d][tx * 4];
                s[0][0] = fmaf(a.x, p.x, s[0][0]); s[0][1] = fmaf(a.x, p.y, s[0][1]);
                s[0][2] = fmaf(a.x, p.z, s[0][2]); s[0][3] = fmaf(a.x, p.w, s[0][3]);
                s[1][0] = fmaf(a.y, p.x, s[1][0]); s[1][1] = fmaf(a.y, p.y, s[1][1]);
                s[1][2] = fmaf(a.y, p.z, s[1][2]); s[1][3] = fmaf(a.y, p.w, s[1][3]);
                s[2][0] = fmaf(a.z, p.x, s[2][0]); s[2][1] = fmaf(a.z, p.y, s[2][1]);
                s[2][2] = fmaf(a.z, p.z, s[2][2]); s[2][3] = fmaf(a.z, p.w, s[2][3]);
                s[3][0] = fmaf(a.w, p.x, s[3][0]); s[3][1] = fmaf(a.w, p.y, s[3][1]);
                s[3][2] = fmaf(a.w, p.z, s[3][2]); s[3][3] = fmaf(a.w, p.w, s[3][3]);
            }
#pragma unroll
            for (int i = 0; i < 4; ++i) {
                float4 e;
                e.x = __expf(s[i][0]) + 1e-6f; e.y = __expf(s[i][1]) + 1e-6f;
                e.z = __expf(s[i][2]) + 1e-6f; e.w = __expf(s[i][3]) + 1e-6f;
                *(float4*)&Kps[ty * 4 + i][tx * 4] = e;
            }
            __syncthreads();
            // KV[f][d] += sum_t Kp[t][f] * V[t][d]
#pragma unroll 8
            for (int t = 0; t < 64; ++t) {
                float4 a = *(float4*)&Kps[t][ty * 4];
                float4 v = *(float4*)&Vs[t][tx * 4];
                kv[fc][0][0] = fmaf(a.x, v.x, kv[fc][0][0]); kv[fc][0][1] = fmaf(a.x, v.y, kv[fc][0][1]);
                kv[fc][0][2] = fmaf(a.x, v.z, kv[fc][0][2]); kv[fc][0][3] = fmaf(a.x, v.w, kv[fc][0][3]);
                kv[fc][1][0] = fmaf(a.y, v.x, kv[fc][1][0]); kv[fc][1][1] = fmaf(a.y, v.y, kv[fc][1][1]);
                kv[fc][1][2] = fmaf(a.y, v.z, kv[fc][1][2]); kv[fc][1][3] = fmaf(a.y, v.w, kv[fc][1][3]);
                kv[fc][2][0] = fmaf(a.z, v.x, kv[fc][2][0]); kv[fc][2][1] = fmaf(a.z, v.y, kv[fc][2][1]);
                kv[fc][2][2] = fmaf(a.z, v.z, kv[fc][2][2]); kv[fc][2][3] = fmaf(a.z, v.w, kv[fc][2][3]);
                kv[fc][3][0] = fmaf(a.w, v.x, kv[fc][3][0]); kv[fc][3][1] = fmaf(a.w, v.y, kv[fc][3][1]);
                kv[fc][3][2] = fmaf(a.w, v.z, kv[fc][3][2]); kv[fc][3][3] = fmaf(a.w, v.w, kv[fc][3][3]);
            }
            // Ksum partial: wave 'fc' sums its own f-chunk (f_global = tid)
            if (myfc == fc) {
                float ss = 0.f;
#pragma unroll 8
                for (int t = 0; t < 64; ++t) ss += Kps[t][lane];
                ksum_acc += ss;
            }
        }
    }
    const size_t base = (size_t)(b * kH + h) * kF;
#pragma unroll
    for (int fc = 0; fc < 4; ++fc)
#pragma unroll
        for (int i = 0; i < 4; ++i)
#pragma unroll
            for (int j = 0; j < 4; ++j)
                atomicAdd(&KVg[(base + fc * 64 + ty * 4 + i) * kD + tx * 4 + j], kv[fc][i][j]);
    atomicAdd(&Ksumg[base + tid], ksum_acc);
}

// ---------------------------------------------------------------- Phase B: attn[bt][h*64+d]
__global__ __launch_bounds__(256) void phaseB_kernel(const float* __restrict__ Qg,
                                                     const float* __restrict__ proj,
                                                     const float* __restrict__ KVg,
                                                     const float* __restrict__ Ksumg,
                                                     float* __restrict__ attng) {
    __shared__ float Qsd[64][68];   // [d][t]
    __shared__ float Pjd[64][68];   // [d][f]
    __shared__ float QpT[64][68];   // [f][t]
    __shared__ float KVs[64][68];   // [f][d]
    __shared__ float Ksum_s[256];
    __shared__ float den[4][64];
    const int tid = threadIdx.x;
    const int tx = tid & 15, ty = tid >> 4;
    const int bh = blockIdx.x;
    const int b = bh >> 4, h = bh & 15;
    const int grp = blockIdx.y;
    const int myfc = tid >> 6, lane = tid & 63;
    const size_t base = (size_t)(b * kH + h) * kF;
    Ksum_s[tid] = Ksumg[base + tid];

    for (int it = 0; it < 8; ++it) {
        const int t0 = grp * 512 + it * 64;
        __syncthreads();
#pragma unroll
        for (int r = 0; r < 4; ++r) {
            int lin = r * 256 + tid;
            int t = lin >> 4;
            int d4 = (lin & 15) << 2;
            float4 q4 = *(const float4*)(Qg + (size_t)(b * kT + t0 + t) * kE + h * kD + d4);
            Qsd[d4 + 0][t] = q4.x; Qsd[d4 + 1][t] = q4.y;
            Qsd[d4 + 2][t] = q4.z; Qsd[d4 + 3][t] = q4.w;
        }
        float nm[4][4] = {};
        float dn = 0.f;
        for (int fc = 0; fc < 4; ++fc) {
            __syncthreads();
#pragma unroll
            for (int r = 0; r < 4; ++r) {
                int lin = r * 256 + tid;
                int f = lin >> 4;
                int d4 = (lin & 15) << 2;
                float4 p4 = *(const float4*)(proj + (size_t)(fc * 64 + f) * kD + d4);
                Pjd[d4 + 0][f] = p4.x; Pjd[d4 + 1][f] = p4.y;
                Pjd[d4 + 2][f] = p4.z; Pjd[d4 + 3][f] = p4.w;
                *(float4*)&KVs[f][d4] = *(const float4*)(KVg + (base + fc * 64 + f) * kD + d4);
            }
            __syncthreads();
            float s[4][4] = {};
#pragma unroll 8
            for (int d = 0; d < 64; ++d) {
                float4 a = *(float4*)&Qsd[d][ty * 4];
                float4 p = *(float4*)&Pjd[d][tx * 4];
                s[0][0] = fmaf(a.x, p.x, s[0][0]); s[0][1] = fmaf(a.x, p.y, s[0][1]);
                s[0][2] = fmaf(a.x, p.z, s[0][2]); s[0][3] = fmaf(a.x, p.w, s[0][3]);
                s[1][0] = fmaf(a.y, p.x, s[1][0]); s[1][1] = fmaf(a.y, p.y, s[1][1]);
                s[1][2] = fmaf(a.y, p.z, s[1][2]); s[1][3] = fmaf(a.y, p.w, s[1][3]);
                s[2][0] = fmaf(a.z, p.x, s[2][0]); s[2][1] = fmaf(a.z, p.y, s[2][1]);
                s[2][2] = fmaf(a.z, p.z, s[2][2]); s[2][3] = fmaf(a.z, p.w, s[2][3]);
                s[3][0] = fmaf(a.w, p.x, s[3][0]); s[3][1] = fmaf(a.w, p.y, s[3][1]);
                s[3][2] = fmaf(a.w, p.z, s[3][2]); s[3][3] = fmaf(a.w, p.w, s[3][3]);
            }
            // store Qp transposed: QpT[f][t]
#pragma unroll
            for (int j = 0; j < 4; ++j) {
                float4 e;
                e.x = __expf(s[0][j]) + 1e-6f; e.y = __expf(s[1][j]) + 1e-6f;
                e.z = __expf(s[2][j]) + 1e-6f; e.w = __expf(s[3][j]) + 1e-6f;
                *(float4*)&QpT[tx * 4 + j][ty * 4] = e;
            }
            __syncthreads();
            // numer[t][d] += sum_f Qp[t][f] * KV[f][d]
#pragma unroll 8
            for (int f = 0; f < 64; ++f) {
                float4 a = *(float4*)&QpT[f][ty * 4];
                float4 v = *(float4*)&KVs[f][tx * 4];
                nm[0][0] = fmaf(a.x, v.x, nm[0][0]); nm[0][1] = fmaf(a.x, v.y, nm[0][1]);
                nm[0][2] = fmaf(a.x, v.z, nm[0][2]); nm[0][3] = fmaf(a.x, v.w, nm[0][3]);
                nm[1][0] = fmaf(a.y, v.x, nm[1][0]); nm[1][1] = fmaf(a.y, v.y, nm[1][1]);
                nm[1][2] = fmaf(a.y, v.z, nm[1][2]); nm[1][3] = fmaf(a.y, v.w, nm[1][3]);
                nm[2][0] = fmaf(a.z, v.x, nm[2][0]); nm[2][1] = fmaf(a.z, v.y, nm[2][1]);
                nm[2][2] = fmaf(a.z, v.z, nm[2][2]); nm[2][3] = fmaf(a.z, v.w, nm[2][3]);
                nm[3][0] = fmaf(a.w, v.x, nm[3][0]); nm[3][1] = fmaf(a.w, v.y, nm[3][1]);
                nm[3][2] = fmaf(a.w, v.z, nm[3][2]); nm[3][3] = fmaf(a.w, v.w, nm[3][3]);
            }
            if (myfc == fc) {
                float ss = 0.f;
#pragma unroll 8
                for (int f = 0; f < 64; ++f) ss += QpT[f][lane] * Ksum_s[fc * 64 + f];
                dn += ss;
            }
        }
        den[myfc][lane] = dn;
        __syncthreads();
#pragma unroll
        for (int i = 0; i < 4; ++i) {
            int t = ty * 4 + i;
            float dt = den[0][t] + den[1][t] + den[2][t] + den[3][t];
            float r = 1.f / fmaxf(dt, 1e-6f);
            float4 o = make_float4(nm[i][0] * r, nm[i][1] * r, nm[i][2] * r, nm[i][3] * r);
            *(float4*)(attng + (size_t)(b * kT + t0 + t) * kE + h * kD + tx * 4) = o;
        }
    }
}

// ---------------------------------------------------------------- launch
extern "C" void kernel_launch(void* const* d_in, const int* in_sizes, int n_in,
                              void* d_out, int out_size, void* d_ws, size_t ws_size,
                              hipStream_t stream) {
    (void)in_sizes; (void)n_in; (void)out_size; (void)ws_size;
    const float* x    = (const float*)d_in[0];
    const float* Wq   = (const float*)d_in[1];
    const float* Wk   = (const float*)d_in[2];
    const float* Wv   = (const float*)d_in[3];
    const float* Wo   = (const float*)d_in[4];
    const float* proj = (const float*)d_in[5];
    float* out = (float*)d_out;

    float* Q    = (float*)d_ws;
    float* K    = Q + (size_t)16384 * 1024;
    float* V    = K + (size_t)16384 * 1024;      // reused as attn after phase A
    float* KV   = V + (size_t)16384 * 1024;      // 4*16*256*64
    float* Ksum = KV + (size_t)4 * 16 * 256 * 64;

    const int nz = 4 * 16 * 256 * 64 + 4 * 16 * 256;
    zero_kernel<<<dim3((nz + 255) / 256), 256, 0, stream>>>(KV, nz);
    copy_x_kernel<<<dim3(8192), 256, 0, stream>>>(x, out);

    dim3 gg(8, 128);  // N-tiles x M-tiles
    gemm_xw_kernel<<<gg, 256, 0, stream>>>(x, Wq, Q);
    gemm_xw_kernel<<<gg, 256, 0, stream>>>(x, Wk, K);
    gemm_xw_kernel<<<gg, 256, 0, stream>>>(x, Wv, V);

    phaseA_kernel<<<dim3(64, 8), 256, 0, stream>>>(K, V, proj, KV, Ksum);
    phaseB_kernel<<<dim3(64, 8), 256, 0, stream>>>(Q, proj, KV, Ksum, V /*attn*/);

    gemm_ao_kernel<<<gg, 256, 0, stream>>>(V /*attn*/, Wo, out);
}

// Round 2
// 916.459 us; speedup vs baseline: 1.9147x; 1.9147x over previous
//
#include <hip/hip_runtime.h>

// PerformerAttnBlock — Round 2: bf16-MFMA GEMMs (QKV fused + Wo), fp32 phases.
// B=4, IN=512, T=4096, EMBED=1024, H=16, D=64, F=256.
// WS layout (bytes):
//   0         : QKV fp32 [16384][3072] (192MB)  -- C2 fp32 [16384][1024] aliases it
//   201326592 : attn bf16 [16384][1024] (32MB)  -- A_bf16 [16384][512] aliases it
//   234881024 : Bt_qkv bf16 [3072][512] (3MB)
//   238026752 : WoT bf16 [1024][1024] (2MB)
//   240123904 : KV fp32 [64][256][64] (16MB)
//   256901120 : Ksum fp32 [64][256] (64KB)      -- end 245.06 MB

constexpr int kB  = 4;
constexpr int kIn = 512;
constexpr int kT  = 4096;
constexpr int kE  = 1024;
constexpr int kH  = 16;
constexpr int kD  = 64;
constexpr int kF  = 256;
constexpr int kQKVs = 3072;   // fused QKV row stride

typedef __attribute__((ext_vector_type(8))) short bf16x8;
typedef __attribute__((ext_vector_type(4))) float f32x4;

__device__ __forceinline__ unsigned short f2bf(float f) {
    unsigned u = __float_as_uint(f);
    u += 0x7fff + ((u >> 16) & 1);          // round-to-nearest-even
    return (unsigned short)(u >> 16);
}

__device__ __forceinline__ void gload_lds16(const void* g, void* l) {
    __builtin_amdgcn_global_load_lds((const __attribute__((address_space(1))) void*)g,
                                     (__attribute__((address_space(3))) void*)l, 16, 0, 0);
}

// ---------------------------------------------------------------- zero
__global__ __launch_bounds__(256) void zero_kernel(float* __restrict__ p, int n) {
    int i = blockIdx.x * 256 + threadIdx.x;
    if (i < n) p[i] = 0.f;
}

// ---------------------------------------------------------------- copy x -> out[:, :512, :]
__global__ __launch_bounds__(256) void copy_x_kernel(const float* __restrict__ x,
                                                     float* __restrict__ out) {
    const int perB4 = kIn * kT / 4;
    int idx = blockIdx.x * 256 + threadIdx.x;
    if (idx < kB * perB4) {
        int b = idx / perB4, e = idx % perB4;
        ((float4*)out)[(size_t)b * ((kIn + kE) * kT / 4) + e] = ((const float4*)x)[idx];
    }
}

// ---------------------------------------------------------------- generic transpose + fp32->bf16
// src [R][C] fp32 (+z*sstride), dst [C][R] bf16 (+z*dstride): dst[c][r] = src[r][c]
__global__ __launch_bounds__(256) void trans_f2b_kernel(const float* __restrict__ src,
                                                        unsigned short* __restrict__ dst,
                                                        int R, int C,
                                                        long sstride, long dstride) {
    __shared__ float L[64][68];
    src += (size_t)blockIdx.z * sstride;
    dst += (size_t)blockIdx.z * dstride;
    const int c0 = blockIdx.x * 64, r0 = blockIdx.y * 64;
    const int tid = threadIdx.x;
#pragma unroll
    for (int it = 0; it < 4; ++it) {
        int lin = it * 256 + tid;
        int i = lin >> 4;            // r
        int j4 = (lin & 15) * 4;     // c
        float4 v = *(const float4*)(src + (size_t)(r0 + i) * C + c0 + j4);
        L[j4 + 0][i] = v.x; L[j4 + 1][i] = v.y; L[j4 + 2][i] = v.z; L[j4 + 3][i] = v.w;
    }
    __syncthreads();
#pragma unroll
    for (int it = 0; it < 4; ++it) {
        int lin = it * 256 + tid;
        int cc = lin >> 4;
        int r4 = (lin & 15) * 4;
        ushort4 o;
        o.x = f2bf(L[cc][r4 + 0]); o.y = f2bf(L[cc][r4 + 1]);
        o.z = f2bf(L[cc][r4 + 2]); o.w = f2bf(L[cc][r4 + 3]);
        *(ushort4*)(dst + (size_t)(c0 + cc) * R + r0 + r4) = o;
    }
}

// ---------------------------------------------------------------- bf16 MFMA GEMM (m97-style)
// A [M][K] bf16 row-major, Bt [N][K] bf16 row-major, C [M][N] fp32.
// 128x128 block tile, BK=64, 4 waves (each 64x64), 16x16x32 MFMA.
__global__ __launch_bounds__(256) void gemm_mfma_kernel(const short* __restrict__ A,
                                                        const short* __restrict__ Bt,
                                                        float* __restrict__ C,
                                                        int N, int K) {
    __shared__ short As[128 * 64];
    __shared__ short Bs[128 * 64];
    const int tid = threadIdx.x;
    const int lane = tid & 63, w = tid >> 6;
    const int n0 = blockIdx.x * 128, m0 = blockIdx.y * 128;
    const int wm = (w >> 1) * 64, wn = (w & 1) * 64;
    f32x4 acc[4][4];
#pragma unroll
    for (int i = 0; i < 4; ++i)
#pragma unroll
        for (int j = 0; j < 4; ++j) acc[i][j] = (f32x4){0.f, 0.f, 0.f, 0.f};

    // staging chunk: instruction i of wave w covers 16B-chunks p=(i*4+w)*64+lane;
    // chunk p -> row=p>>3, col-chunk c=p&7 (contiguous [row][64] LDS layout).
    const int row_a[4] = { ((0 * 4 + w) * 64 + lane) >> 3, ((1 * 4 + w) * 64 + lane) >> 3,
                           ((2 * 4 + w) * 64 + lane) >> 3, ((3 * 4 + w) * 64 + lane) >> 3 };
    const int col_a[4] = { (lane & 7) * 8, (lane & 7) * 8, (lane & 7) * 8, (lane & 7) * 8 };

    for (int k0 = 0; k0 < K; k0 += 64) {
        __syncthreads();
#pragma unroll
        for (int i = 0; i < 4; ++i) {
            gload_lds16(A + (size_t)(m0 + row_a[i]) * K + k0 + col_a[i], &As[(i * 4 + w) * 512]);
            gload_lds16(Bt + (size_t)(n0 + row_a[i]) * K + k0 + col_a[i], &Bs[(i * 4 + w) * 512]);
        }
        __syncthreads();
#pragma unroll
        for (int s = 0; s < 2; ++s) {
            const int kc = s * 32 + (lane >> 4) * 8;
            bf16x8 av[4], bv[4];
#pragma unroll
            for (int i = 0; i < 4; ++i)
                av[i] = *(const bf16x8*)&As[(wm + i * 16 + (lane & 15)) * 64 + kc];
#pragma unroll
            for (int j = 0; j < 4; ++j)
                bv[j] = *(const bf16x8*)&Bs[(wn + j * 16 + (lane & 15)) * 64 + kc];
#pragma unroll
            for (int i = 0; i < 4; ++i)
#pragma unroll
                for (int j = 0; j < 4; ++j)
                    acc[i][j] = __builtin_amdgcn_mfma_f32_16x16x32_bf16(av[i], bv[j], acc[i][j], 0, 0, 0);
        }
    }
    const int col = lane & 15, qr = lane >> 4;
#pragma unroll
    for (int i = 0; i < 4; ++i)
#pragma unroll
        for (int j = 0; j < 4; ++j)
#pragma unroll
            for (int r = 0; r < 4; ++r)
                C[(size_t)(m0 + wm + i * 16 + qr * 4 + r) * N + n0 + wn + j * 16 + col] = acc[i][j][r];
}

// ---------------------------------------------------------------- out transpose: C2[16384][1024] -> out[b][512+n][t]
__global__ __launch_bounds__(256) void out_transpose_kernel(const float* __restrict__ C2,
                                                            float* __restrict__ out) {
    __shared__ float L[64][68];
    const int t0 = blockIdx.x * 64;
    const int n0 = (blockIdx.y & 15) * 64;
    const int b = blockIdx.y >> 4;
    const float* src = C2 + (size_t)b * kT * kE;
    float* dst = out + (size_t)b * (kIn + kE) * kT + (size_t)kIn * kT;
    const int tid = threadIdx.x;
#pragma unroll
    for (int it = 0; it < 4; ++it) {
        int lin = it * 256 + tid;
        int i = lin >> 4;            // t
        int j4 = (lin & 15) * 4;     // n
        float4 v = *(const float4*)(src + (size_t)(t0 + i) * kE + n0 + j4);
        L[j4 + 0][i] = v.x; L[j4 + 1][i] = v.y; L[j4 + 2][i] = v.z; L[j4 + 3][i] = v.w;
    }
    __syncthreads();
#pragma unroll
    for (int it = 0; it < 4; ++it) {
        int lin = it * 256 + tid;
        int nn = lin >> 4;
        int t4 = (lin & 15) * 4;
        *(float4*)(dst + (size_t)(n0 + nn) * kT + t0 + t4) = *(const float4*)&L[nn][t4];
    }
}

// ---------------------------------------------------------------- Phase A: KV[b,h,f,d], Ksum[b,h,f]
__global__ __launch_bounds__(256) void phaseA_kernel(const float* __restrict__ QKVg,
                                                     const float* __restrict__ proj,
                                                     float* __restrict__ KVg,
                                                     float* __restrict__ Ksumg) {
    __shared__ float Ksd[64][68];   // [d][t]
    __shared__ float Vs[64][68];    // [t][d]
    __shared__ float Pjd[64][68];   // [d][f]
    __shared__ float Kps[64][68];   // [t][f]
    const int tid = threadIdx.x;
    const int tx = tid & 15, ty = tid >> 4;
    const int bh = blockIdx.x;
    const int b = bh >> 4, h = bh & 15;
    const int grp = blockIdx.y;
    const int myfc = tid >> 6, lane = tid & 63;

    float kv[4][4][4];
#pragma unroll
    for (int fc = 0; fc < 4; ++fc)
#pragma unroll
        for (int i = 0; i < 4; ++i)
#pragma unroll
            for (int j = 0; j < 4; ++j) kv[fc][i][j] = 0.f;
    float ksum_acc = 0.f;

    for (int it = 0; it < 8; ++it) {
        const int t0 = grp * 512 + it * 64;
        __syncthreads();
#pragma unroll
        for (int r = 0; r < 4; ++r) {
            int lin = r * 256 + tid;
            int t = lin >> 4;
            int d4 = (lin & 15) << 2;
            size_t goff = (size_t)(b * kT + t0 + t) * kQKVs + h * kD + d4;
            float4 k4 = *(const float4*)(QKVg + goff + 1024);   // K block
            Ksd[d4 + 0][t] = k4.x; Ksd[d4 + 1][t] = k4.y;
            Ksd[d4 + 2][t] = k4.z; Ksd[d4 + 3][t] = k4.w;
            *(float4*)&Vs[t][d4] = *(const float4*)(QKVg + goff + 2048);  // V block
        }
#pragma unroll
        for (int fc = 0; fc < 4; ++fc) {
            __syncthreads();
#pragma unroll
            for (int r = 0; r < 4; ++r) {
                int lin = r * 256 + tid;
                int f = lin >> 4;
                int d4 = (lin & 15) << 2;
                float4 p4 = *(const float4*)(proj + (size_t)(fc * 64 + f) * kD + d4);
                Pjd[d4 + 0][f] = p4.x; Pjd[d4 + 1][f] = p4.y;
                Pjd[d4 + 2][f] = p4.z; Pjd[d4 + 3][f] = p4.w;
            }
            __syncthreads();
            float s[4][4] = {};
#pragma unroll 8
            for (int d = 0; d < 64; ++d) {
                float4 a = *(float4*)&Ksd[d][ty * 4];
                float4 p = *(float4*)&Pjd[d][tx * 4];
                s[0][0] = fmaf(a.x, p.x, s[0][0]); s[0][1] = fmaf(a.x, p.y, s[0][1]);
                s[0][2] = fmaf(a.x, p.z, s[0][2]); s[0][3] = fmaf(a.x, p.w, s[0][3]);
                s[1][0] = fmaf(a.y, p.x, s[1][0]); s[1][1] = fmaf(a.y, p.y, s[1][1]);
                s[1][2] = fmaf(a.y, p.z, s[1][2]); s[1][3] = fmaf(a.y, p.w, s[1][3]);
                s[2][0] = fmaf(a.z, p.x, s[2][0]); s[2][1] = fmaf(a.z, p.y, s[2][1]);
                s[2][2] = fmaf(a.z, p.z, s[2][2]); s[2][3] = fmaf(a.z, p.w, s[2][3]);
                s[3][0] = fmaf(a.w, p.x, s[3][0]); s[3][1] = fmaf(a.w, p.y, s[3][1]);
                s[3][2] = fmaf(a.w, p.z, s[3][2]); s[3][3] = fmaf(a.w, p.w, s[3][3]);
            }
#pragma unroll
            for (int i = 0; i < 4; ++i) {
                float4 e;
                e.x = __expf(s[i][0]) + 1e-6f; e.y = __expf(s[i][1]) + 1e-6f;
                e.z = __expf(s[i][2]) + 1e-6f; e.w = __expf(s[i][3]) + 1e-6f;
                *(float4*)&Kps[ty * 4 + i][tx * 4] = e;
            }
            __syncthreads();
#pragma unroll 8
            for (int t = 0; t < 64; ++t) {
                float4 a = *(float4*)&Kps[t][ty * 4];
                float4 v = *(float4*)&Vs[t][tx * 4];
                kv[fc][0][0] = fmaf(a.x, v.x, kv[fc][0][0]); kv[fc][0][1] = fmaf(a.x, v.y, kv[fc][0][1]);
                kv[fc][0][2] = fmaf(a.x, v.z, kv[fc][0][2]); kv[fc][0][3] = fmaf(a.x, v.w, kv[fc][0][3]);
                kv[fc][1][0] = fmaf(a.y, v.x, kv[fc][1][0]); kv[fc][1][1] = fmaf(a.y, v.y, kv[fc][1][1]);
                kv[fc][1][2] = fmaf(a.y, v.z, kv[fc][1][2]); kv[fc][1][3] = fmaf(a.y, v.w, kv[fc][1][3]);
                kv[fc][2][0] = fmaf(a.z, v.x, kv[fc][2][0]); kv[fc][2][1] = fmaf(a.z, v.y, kv[fc][2][1]);
                kv[fc][2][2] = fmaf(a.z, v.z, kv[fc][2][2]); kv[fc][2][3] = fmaf(a.z, v.w, kv[fc][2][3]);
                kv[fc][3][0] = fmaf(a.w, v.x, kv[fc][3][0]); kv[fc][3][1] = fmaf(a.w, v.y, kv[fc][3][1]);
                kv[fc][3][2] = fmaf(a.w, v.z, kv[fc][3][2]); kv[fc][3][3] = fmaf(a.w, v.w, kv[fc][3][3]);
            }
            if (myfc == fc) {
                float ss = 0.f;
#pragma unroll 8
                for (int t = 0; t < 64; ++t) ss += Kps[t][lane];
                ksum_acc += ss;
            }
        }
    }
    const size_t base = (size_t)(b * kH + h) * kF;
#pragma unroll
    for (int fc = 0; fc < 4; ++fc)
#pragma unroll
        for (int i = 0; i < 4; ++i)
#pragma unroll
            for (int j = 0; j < 4; ++j)
                atomicAdd(&KVg[(base + fc * 64 + ty * 4 + i) * kD + tx * 4 + j], kv[fc][i][j]);
    atomicAdd(&Ksumg[base + tid], ksum_acc);
}

// ---------------------------------------------------------------- Phase B: attn (bf16) [16384][1024]
__global__ __launch_bounds__(256) void phaseB_kernel(const float* __restrict__ QKVg,
                                                     const float* __restrict__ proj,
                                                     const float* __restrict__ KVg,
                                                     const float* __restrict__ Ksumg,
                                                     unsigned short* __restrict__ attnb) {
    __shared__ float Qsd[64][68];
    __shared__ float Pjd[64][68];
    __shared__ float QpT[64][68];
    __shared__ float KVs[64][68];
    __shared__ float Ksum_s[256];
    __shared__ float den[4][64];
    const int tid = threadIdx.x;
    const int tx = tid & 15, ty = tid >> 4;
    const int bh = blockIdx.x;
    const int b = bh >> 4, h = bh & 15;
    const int grp = blockIdx.y;
    const int myfc = tid >> 6, lane = tid & 63;
    const size_t base = (size_t)(b * kH + h) * kF;
    Ksum_s[tid] = Ksumg[base + tid];

    for (int it = 0; it < 8; ++it) {
        const int t0 = grp * 512 + it * 64;
        __syncthreads();
#pragma unroll
        for (int r = 0; r < 4; ++r) {
            int lin = r * 256 + tid;
            int t = lin >> 4;
            int d4 = (lin & 15) << 2;
            float4 q4 = *(const float4*)(QKVg + (size_t)(b * kT + t0 + t) * kQKVs + h * kD + d4);
            Qsd[d4 + 0][t] = q4.x; Qsd[d4 + 1][t] = q4.y;
            Qsd[d4 + 2][t] = q4.z; Qsd[d4 + 3][t] = q4.w;
        }
        float nm[4][4] = {};
        float dn = 0.f;
        for (int fc = 0; fc < 4; ++fc) {
            __syncthreads();
#pragma unroll
            for (int r = 0; r < 4; ++r) {
                int lin = r * 256 + tid;
                int f = lin >> 4;
                int d4 = (lin & 15) << 2;
                float4 p4 = *(const float4*)(proj + (size_t)(fc * 64 + f) * kD + d4);
                Pjd[d4 + 0][f] = p4.x; Pjd[d4 + 1][f] = p4.y;
                Pjd[d4 + 2][f] = p4.z; Pjd[d4 + 3][f] = p4.w;
                *(float4*)&KVs[f][d4] = *(const float4*)(KVg + (base + fc * 64 + f) * kD + d4);
            }
            __syncthreads();
            float s[4][4] = {};
#pragma unroll 8
            for (int d = 0; d < 64; ++d) {
                float4 a = *(float4*)&Qsd[d][ty * 4];
                float4 p = *(float4*)&Pjd[d][tx * 4];
                s[0][0] = fmaf(a.x, p.x, s[0][0]); s[0][1] = fmaf(a.x, p.y, s[0][1]);
                s[0][2] = fmaf(a.x, p.z, s[0][2]); s[0][3] = fmaf(a.x, p.w, s[0][3]);
                s[1][0] = fmaf(a.y, p.x, s[1][0]); s[1][1] = fmaf(a.y, p.y, s[1][1]);
                s[1][2] = fmaf(a.y, p.z, s[1][2]); s[1][3] = fmaf(a.y, p.w, s[1][3]);
                s[2][0] = fmaf(a.z, p.x, s[2][0]); s[2][1] = fmaf(a.z, p.y, s[2][1]);
                s[2][2] = fmaf(a.z, p.z, s[2][2]); s[2][3] = fmaf(a.z, p.w, s[2][3]);
                s[3][0] = fmaf(a.w, p.x, s[3][0]); s[3][1] = fmaf(a.w, p.y, s[3][1]);
                s[3][2] = fmaf(a.w, p.z, s[3][2]); s[3][3] = fmaf(a.w, p.w, s[3][3]);
            }
#pragma unroll
            for (int j = 0; j < 4; ++j) {
                float4 e;
                e.x = __expf(s[0][j]) + 1e-6f; e.y = __expf(s[1][j]) + 1e-6f;
                e.z = __expf(s[2][j]) + 1e-6f; e.w = __expf(s[3][j]) + 1e-6f;
                *(float4*)&QpT[tx * 4 + j][ty * 4] = e;
            }
            __syncthreads();
#pragma unroll 8
            for (int f = 0; f < 64; ++f) {
                float4 a = *(float4*)&QpT[f][ty * 4];
                float4 v = *(float4*)&KVs[f][tx * 4];
                nm[0][0] = fmaf(a.x, v.x, nm[0][0]); nm[0][1] = fmaf(a.x, v.y, nm[0][1]);
                nm[0][2] = fmaf(a.x, v.z, nm[0][2]); nm[0][3] = fmaf(a.x, v.w, nm[0][3]);
                nm[1][0] = fmaf(a.y, v.x, nm[1][0]); nm[1][1] = fmaf(a.y, v.y, nm[1][1]);
                nm[1][2] = fmaf(a.y, v.z, nm[1][2]); nm[1][3] = fmaf(a.y, v.w, nm[1][3]);
                nm[2][0] = fmaf(a.z, v.x, nm[2][0]); nm[2][1] = fmaf(a.z, v.y, nm[2][1]);
                nm[2][2] = fmaf(a.z, v.z, nm[2][2]); nm[2][3] = fmaf(a.z, v.w, nm[2][3]);
                nm[3][0] = fmaf(a.w, v.x, nm[3][0]); nm[3][1] = fmaf(a.w, v.y, nm[3][1]);
                nm[3][2] = fmaf(a.w, v.z, nm[3][2]); nm[3][3] = fmaf(a.w, v.w, nm[3][3]);
            }
            if (myfc == fc) {
                float ss = 0.f;
#pragma unroll 8
                for (int f = 0; f < 64; ++f) ss += QpT[f][lane] * Ksum_s[fc * 64 + f];
                dn += ss;
            }
        }
        den[myfc][lane] = dn;
        __syncthreads();
#pragma unroll
        for (int i = 0; i < 4; ++i) {
            int t = ty * 4 + i;
            float dt = den[0][t] + den[1][t] + den[2][t] + den[3][t];
            float r = 1.f / fmaxf(dt, 1e-6f);
            ushort4 o;
            o.x = f2bf(nm[i][0] * r); o.y = f2bf(nm[i][1] * r);
            o.z = f2bf(nm[i][2] * r); o.w = f2bf(nm[i][3] * r);
            *(ushort4*)(attnb + (size_t)(b * kT + t0 + t) * kE + h * kD + tx * 4) = o;
        }
    }
}

// ---------------------------------------------------------------- launch
extern "C" void kernel_launch(void* const* d_in, const int* in_sizes, int n_in,
                              void* d_out, int out_size, void* d_ws, size_t ws_size,
                              hipStream_t stream) {
    (void)in_sizes; (void)n_in; (void)out_size; (void)ws_size;
    const float* x    = (const float*)d_in[0];
    const float* Wq   = (const float*)d_in[1];
    const float* Wk   = (const float*)d_in[2];
    const float* Wv   = (const float*)d_in[3];
    const float* Wo   = (const float*)d_in[4];
    const float* proj = (const float*)d_in[5];
    float* out = (float*)d_out;

    char* ws = (char*)d_ws;
    float*          QKV   = (float*)(ws);                        // 192MB; C2 aliases
    float*          C2    = (float*)(ws);
    unsigned short* attnb = (unsigned short*)(ws + 201326592);   // 32MB; Abuf aliases
    unsigned short* Abuf  = (unsigned short*)(ws + 201326592);
    unsigned short* Btqkv = (unsigned short*)(ws + 234881024);   // 3MB
    unsigned short* WoT   = (unsigned short*)(ws + 238026752);   // 2MB
    float*          KV    = (float*)(ws + 240123904);            // 16MB
    float*          Ksum  = (float*)(ws + 256901120);            // 64KB

    // x passthrough into out channels [0,512)
    copy_x_kernel<<<dim3(8192), 256, 0, stream>>>(x, out);

    // bf16 conversions (all transposed): A[t][k], Bt[n][k], WoT[n][k]
    trans_f2b_kernel<<<dim3(64, 8, 4), 256, 0, stream>>>(x, Abuf, kIn, kT,
                                                         (long)kIn * kT, (long)kT * kIn);
    trans_f2b_kernel<<<dim3(16, 8, 1), 256, 0, stream>>>(Wq, Btqkv, kIn, kE, 0, 0);
    trans_f2b_kernel<<<dim3(16, 8, 1), 256, 0, stream>>>(Wk, Btqkv + (size_t)kE * kIn, kIn, kE, 0, 0);
    trans_f2b_kernel<<<dim3(16, 8, 1), 256, 0, stream>>>(Wv, Btqkv + (size_t)2 * kE * kIn, kIn, kE, 0, 0);
    trans_f2b_kernel<<<dim3(16, 16, 1), 256, 0, stream>>>(Wo, WoT, kE, kE, 0, 0);

    // fused QKV GEMM: [16384][512] x [3072][512]^T -> [16384][3072] fp32
    gemm_mfma_kernel<<<dim3(24, 128), 256, 0, stream>>>((const short*)Abuf, (const short*)Btqkv,
                                                        QKV, kQKVs, kIn);

    const int nz = kB * kH * kF * kD + kB * kH * kF;
    zero_kernel<<<dim3((nz + 255) / 256), 256, 0, stream>>>(KV, nz);

    phaseA_kernel<<<dim3(64, 8), 256, 0, stream>>>(QKV, proj, KV, Ksum);
    phaseB_kernel<<<dim3(64, 8), 256, 0, stream>>>(QKV, proj, KV, Ksum, attnb);

    // out2 = attn @ Wo : [16384][1024] x [1024][1024]^T -> C2 fp32 (aliases QKV)
    gemm_mfma_kernel<<<dim3(8, 128), 256, 0, stream>>>((const short*)attnb, (const short*)WoT,
                                                       C2, kE, kE);
    out_transpose_kernel<<<dim3(64, 64), 256, 0, stream>>>(C2, out);
}

// Round 3
// 414.951 us; speedup vs baseline: 4.2289x; 2.2086x over previous
//
#include <hip/hip_runtime.h>

// PerformerAttnBlock — Round 3: MFMA everywhere (QKV gemm bf16-out, MFMA phases, Wo gemm).
// B=4, IN=512, T=4096, EMBED=1024, H=16, D=64, F=256.
// WS (bytes):
//   0         QKVb bf16 [16384][3072] (96MB)   -- C2 fp32 [16384][1024] (64MB) aliases after phaseB
//   100663296 attnb bf16 [16384][1024] (32MB)  -- Abuf bf16 [16384][512] aliases before gemm1
//   134217728 Btqkv bf16 [3072][512] (3MB)
//   137363456 WoT bf16 [1024][1024] (2MB)
//   139460608 projb bf16 [256][64] (32KB)
//   139493376 KVg fp32 [64][256][64] (4MB)
//   143687680 Ksumg fp32 [64][256] (64KB)
//   143753216 KVTb bf16 [64][64][256] (2MB)    -- end ~139MB

constexpr int kB  = 4;
constexpr int kIn = 512;
constexpr int kT  = 4096;
constexpr int kE  = 1024;
constexpr int kH  = 16;
constexpr int kD  = 64;
constexpr int kF  = 256;
constexpr int kQKVs = 3072;

typedef __attribute__((ext_vector_type(8))) short bf16x8;
typedef __attribute__((ext_vector_type(4))) float f32x4;

__device__ __forceinline__ unsigned short f2bf(float f) {
    unsigned u = __float_as_uint(f);
    u += 0x7fff + ((u >> 16) & 1);          // RNE
    return (unsigned short)(u >> 16);
}
__device__ __forceinline__ float bf2f(unsigned short s) {
    return __uint_as_float(((unsigned)s) << 16);
}
__device__ __forceinline__ void gload_lds16(const void* g, void* l) {
    __builtin_amdgcn_global_load_lds((const __attribute__((address_space(1))) void*)g,
                                     (__attribute__((address_space(3))) void*)l, 16, 0, 0);
}

// ---------------------------------------------------------------- zero
__global__ __launch_bounds__(256) void zero_kernel(float* __restrict__ p, int n) {
    int i = blockIdx.x * 256 + threadIdx.x;
    if (i < n) p[i] = 0.f;
}

// ---------------------------------------------------------------- copy x -> out[:, :512, :]
__global__ __launch_bounds__(256) void copy_x_kernel(const float* __restrict__ x,
                                                     float* __restrict__ out) {
    const int perB4 = kIn * kT / 4;
    int idx = blockIdx.x * 256 + threadIdx.x;
    if (idx < kB * perB4) {
        int b = idx / perB4, e = idx % perB4;
        ((float4*)out)[(size_t)b * ((kIn + kE) * kT / 4) + e] = ((const float4*)x)[idx];
    }
}

// ---------------------------------------------------------------- flat fp32->bf16
__global__ __launch_bounds__(256) void f2b_flat_kernel(const float* __restrict__ s,
                                                       unsigned short* __restrict__ d, int n4) {
    int i = blockIdx.x * 256 + threadIdx.x;
    if (i < n4) {
        float4 v = ((const float4*)s)[i];
        ushort4 o;
        o.x = f2bf(v.x); o.y = f2bf(v.y); o.z = f2bf(v.z); o.w = f2bf(v.w);
        ((ushort4*)d)[i] = o;
    }
}

// ---------------------------------------------------------------- transpose + fp32->bf16
// src [R][C] fp32 (+z*sstride), dst [C][R] bf16 (+z*dstride)
__global__ __launch_bounds__(256) void trans_f2b_kernel(const float* __restrict__ src,
                                                        unsigned short* __restrict__ dst,
                                                        int R, int C,
                                                        long sstride, long dstride) {
    __shared__ float L[64][68];
    src += (size_t)blockIdx.z * sstride;
    dst += (size_t)blockIdx.z * dstride;
    const int c0 = blockIdx.x * 64, r0 = blockIdx.y * 64;
    const int tid = threadIdx.x;
#pragma unroll
    for (int it = 0; it < 4; ++it) {
        int lin = it * 256 + tid;
        int i = lin >> 4;
        int j4 = (lin & 15) * 4;
        float4 v = *(const float4*)(src + (size_t)(r0 + i) * C + c0 + j4);
        L[j4 + 0][i] = v.x; L[j4 + 1][i] = v.y; L[j4 + 2][i] = v.z; L[j4 + 3][i] = v.w;
    }
    __syncthreads();
#pragma unroll
    for (int it = 0; it < 4; ++it) {
        int lin = it * 256 + tid;
        int cc = lin >> 4;
        int r4 = (lin & 15) * 4;
        ushort4 o;
        o.x = f2bf(L[cc][r4 + 0]); o.y = f2bf(L[cc][r4 + 1]);
        o.z = f2bf(L[cc][r4 + 2]); o.w = f2bf(L[cc][r4 + 3]);
        *(ushort4*)(dst + (size_t)(c0 + cc) * R + r0 + r4) = o;
    }
}

// ---------------------------------------------------------------- bf16 MFMA GEMM, fp32 C
// A [M][K] bf16, Bt [N][K] bf16, C [M][N] fp32. 128x128 tile, BK=64, 4 waves.
__global__ __launch_bounds__(256) void gemm_mfma_f32(const unsigned short* __restrict__ A,
                                                     const unsigned short* __restrict__ Bt,
                                                     float* __restrict__ C,
                                                     int N, int K) {
    __shared__ unsigned short As[128 * 64];
    __shared__ unsigned short Bs[128 * 64];
    const int tid = threadIdx.x;
    const int lane = tid & 63, w = tid >> 6;
    const int n0 = blockIdx.x * 128, m0 = blockIdx.y * 128;
    const int wm = (w >> 1) * 64, wn = (w & 1) * 64;
    f32x4 acc[4][4];
#pragma unroll
    for (int i = 0; i < 4; ++i)
#pragma unroll
        for (int j = 0; j < 4; ++j) acc[i][j] = (f32x4){0.f, 0.f, 0.f, 0.f};
    const int colc = (lane & 7) * 8;
    for (int k0 = 0; k0 < K; k0 += 64) {
        __syncthreads();
#pragma unroll
        for (int i = 0; i < 4; ++i) {
            int row = (((i * 4 + w) * 64 + lane) >> 3);
            gload_lds16(A + (size_t)(m0 + row) * K + k0 + colc, &As[(i * 4 + w) * 512]);
            gload_lds16(Bt + (size_t)(n0 + row) * K + k0 + colc, &Bs[(i * 4 + w) * 512]);
        }
        __syncthreads();
#pragma unroll
        for (int s = 0; s < 2; ++s) {
            const int kc = s * 32 + (lane >> 4) * 8;
            bf16x8 av[4], bv[4];
#pragma unroll
            for (int i = 0; i < 4; ++i)
                av[i] = *(const bf16x8*)&As[(wm + i * 16 + (lane & 15)) * 64 + kc];
#pragma unroll
            for (int j = 0; j < 4; ++j)
                bv[j] = *(const bf16x8*)&Bs[(wn + j * 16 + (lane & 15)) * 64 + kc];
#pragma unroll
            for (int i = 0; i < 4; ++i)
#pragma unroll
                for (int j = 0; j < 4; ++j)
                    acc[i][j] = __builtin_amdgcn_mfma_f32_16x16x32_bf16(av[i], bv[j], acc[i][j], 0, 0, 0);
        }
    }
    const int col = lane & 15, qr = lane >> 4;
#pragma unroll
    for (int i = 0; i < 4; ++i)
#pragma unroll
        for (int j = 0; j < 4; ++j)
#pragma unroll
            for (int r = 0; r < 4; ++r)
                C[(size_t)(m0 + wm + i * 16 + qr * 4 + r) * N + n0 + wn + j * 16 + col] = acc[i][j][r];
}

// ---------------------------------------------------------------- same GEMM, bf16 C
__global__ __launch_bounds__(256) void gemm_mfma_b16(const unsigned short* __restrict__ A,
                                                     const unsigned short* __restrict__ Bt,
                                                     unsigned short* __restrict__ C,
                                                     int N, int K) {
    __shared__ unsigned short As[128 * 64];
    __shared__ unsigned short Bs[128 * 64];
    const int tid = threadIdx.x;
    const int lane = tid & 63, w = tid >> 6;
    const int n0 = blockIdx.x * 128, m0 = blockIdx.y * 128;
    const int wm = (w >> 1) * 64, wn = (w & 1) * 64;
    f32x4 acc[4][4];
#pragma unroll
    for (int i = 0; i < 4; ++i)
#pragma unroll
        for (int j = 0; j < 4; ++j) acc[i][j] = (f32x4){0.f, 0.f, 0.f, 0.f};
    const int colc = (lane & 7) * 8;
    for (int k0 = 0; k0 < K; k0 += 64) {
        __syncthreads();
#pragma unroll
        for (int i = 0; i < 4; ++i) {
            int row = (((i * 4 + w) * 64 + lane) >> 3);
            gload_lds16(A + (size_t)(m0 + row) * K + k0 + colc, &As[(i * 4 + w) * 512]);
            gload_lds16(Bt + (size_t)(n0 + row) * K + k0 + colc, &Bs[(i * 4 + w) * 512]);
        }
        __syncthreads();
#pragma unroll
        for (int s = 0; s < 2; ++s) {
            const int kc = s * 32 + (lane >> 4) * 8;
            bf16x8 av[4], bv[4];
#pragma unroll
            for (int i = 0; i < 4; ++i)
                av[i] = *(const bf16x8*)&As[(wm + i * 16 + (lane & 15)) * 64 + kc];
#pragma unroll
            for (int j = 0; j < 4; ++j)
                bv[j] = *(const bf16x8*)&Bs[(wn + j * 16 + (lane & 15)) * 64 + kc];
#pragma unroll
            for (int i = 0; i < 4; ++i)
#pragma unroll
                for (int j = 0; j < 4; ++j)
                    acc[i][j] = __builtin_amdgcn_mfma_f32_16x16x32_bf16(av[i], bv[j], acc[i][j], 0, 0, 0);
        }
    }
    const int col = lane & 15, qr = lane >> 4;
#pragma unroll
    for (int i = 0; i < 4; ++i)
#pragma unroll
        for (int j = 0; j < 4; ++j)
#pragma unroll
            for (int r = 0; r < 4; ++r)
                C[(size_t)(m0 + wm + i * 16 + qr * 4 + r) * N + n0 + wn + j * 16 + col] =
                    f2bf(acc[i][j][r]);
}

// ---------------------------------------------------------------- out transpose (fp32)
__global__ __launch_bounds__(256) void out_transpose_kernel(const float* __restrict__ C2,
                                                            float* __restrict__ out) {
    __shared__ float L[64][68];
    const int t0 = blockIdx.x * 64;
    const int n0 = (blockIdx.y & 15) * 64;
    const int b = blockIdx.y >> 4;
    const float* src = C2 + (size_t)b * kT * kE;
    float* dst = out + (size_t)b * (kIn + kE) * kT + (size_t)kIn * kT;
    const int tid = threadIdx.x;
#pragma unroll
    for (int it = 0; it < 4; ++it) {
        int lin = it * 256 + tid;
        int i = lin >> 4;
        int j4 = (lin & 15) * 4;
        float4 v = *(const float4*)(src + (size_t)(t0 + i) * kE + n0 + j4);
        L[j4 + 0][i] = v.x; L[j4 + 1][i] = v.y; L[j4 + 2][i] = v.z; L[j4 + 3][i] = v.w;
    }
    __syncthreads();
#pragma unroll
    for (int it = 0; it < 4; ++it) {
        int lin = it * 256 + tid;
        int nn = lin >> 4;
        int t4 = (lin & 15) * 4;
        *(float4*)(dst + (size_t)(n0 + nn) * kT + t0 + t4) = *(const float4*)&L[nn][t4];
    }
}

// ---------------------------------------------------------------- Phase A (MFMA): KV, Ksum
// grid (64 bh, 8 t-groups). Wave w owns f-chunk w. Per 64-t tile:
//   S = K·proj^T (MFMA) -> exp fp32 -> KpT[f][t] bf16 (wave-local) ; Ksum via shfl
//   KV += Kp^T·V (MFMA, A=KpT rows f, Bt=VT rows d). fp32 atomics at end.
__global__ __launch_bounds__(256) void phaseA_mfma(const unsigned short* __restrict__ QKVb,
                                                   const unsigned short* __restrict__ projb,
                                                   float* __restrict__ KVg,
                                                   float* __restrict__ Ksumg) {
    __shared__ unsigned short Ks[64 * 64];     // [t][d]
    __shared__ unsigned short VT[64 * 72];     // [d][t] pad 8
    __shared__ unsigned short KpT[256 * 72];   // [f][t] pad 8
    const int tid = threadIdx.x, lane = tid & 63, w = tid >> 6;
    const int col = lane & 15, quad = lane >> 4;
    const int bh = blockIdx.x, b = bh >> 4, h = bh & 15;
    const int grp = blockIdx.y;
    const int f0 = w * 64;

    bf16x8 bB[2][4];   // proj B-fragments, invariant
#pragma unroll
    for (int s = 0; s < 2; ++s)
#pragma unroll
        for (int j = 0; j < 4; ++j)
            bB[s][j] = *(const bf16x8*)(projb + (size_t)(f0 + j * 16 + col) * 64 + s * 32 + quad * 8);

    f32x4 kvacc[4][4];
#pragma unroll
    for (int i = 0; i < 4; ++i)
#pragma unroll
        for (int j = 0; j < 4; ++j) kvacc[i][j] = (f32x4){0.f, 0.f, 0.f, 0.f};
    float ksum_acc[4] = {0.f, 0.f, 0.f, 0.f};

    for (int it = 0; it < 8; ++it) {
        const size_t rowbase = (size_t)(b * kT + grp * 512 + it * 64) * kQKVs + h * kD;
        __syncthreads();   // protect Ks/VT restage vs prior reads
#pragma unroll
        for (int i2 = 0; i2 < 2; ++i2) {
            int p = (i2 * 4 + w) * 64 + lane;
            gload_lds16(QKVb + rowbase + 1024 + (size_t)(p >> 3) * kQKVs + (p & 7) * 8,
                        &Ks[(i2 * 4 + w) * 512]);
        }
#pragma unroll
        for (int r = 0; r < 4; ++r) {
            int lin = r * 256 + tid;
            int t = lin >> 4, d4 = (lin & 15) * 4;
            ushort4 v = *(const ushort4*)(QKVb + rowbase + 2048 + (size_t)t * kQKVs + d4);
            VT[(d4 + 0) * 72 + t] = v.x; VT[(d4 + 1) * 72 + t] = v.y;
            VT[(d4 + 2) * 72 + t] = v.z; VT[(d4 + 3) * 72 + t] = v.w;
        }
        __syncthreads();
        bf16x8 av[2][4];
#pragma unroll
        for (int s = 0; s < 2; ++s)
#pragma unroll
            for (int i = 0; i < 4; ++i)
                av[s][i] = *(const bf16x8*)&Ks[(i * 16 + col) * 64 + s * 32 + quad * 8];
#pragma unroll
        for (int j = 0; j < 4; ++j) {
            f32x4 sa[4];
#pragma unroll
            for (int i = 0; i < 4; ++i) sa[i] = (f32x4){0.f, 0.f, 0.f, 0.f};
#pragma unroll
            for (int s = 0; s < 2; ++s)
#pragma unroll
                for (int i = 0; i < 4; ++i)
                    sa[i] = __builtin_amdgcn_mfma_f32_16x16x32_bf16(av[s][i], bB[s][j], sa[i], 0, 0, 0);
            const int f = f0 + j * 16 + col;
#pragma unroll
            for (int i = 0; i < 4; ++i) {
                float e0 = __expf(sa[i][0]) + 1e-6f;
                float e1 = __expf(sa[i][1]) + 1e-6f;
                float e2 = __expf(sa[i][2]) + 1e-6f;
                float e3 = __expf(sa[i][3]) + 1e-6f;
                ksum_acc[j] += (e0 + e1) + (e2 + e3);
                ushort4 pk;
                pk.x = f2bf(e0); pk.y = f2bf(e1); pk.z = f2bf(e2); pk.w = f2bf(e3);
                *(ushort4*)&KpT[f * 72 + i * 16 + quad * 4] = pk;   // wave-local rows
            }
        }
#pragma unroll
        for (int s = 0; s < 2; ++s) {   // K-dim = t
            const int kc = s * 32 + quad * 8;
            bf16x8 a2[4], b2[4];
#pragma unroll
            for (int i = 0; i < 4; ++i)
                a2[i] = *(const bf16x8*)&KpT[(f0 + i * 16 + col) * 72 + kc];
#pragma unroll
            for (int jn = 0; jn < 4; ++jn)
                b2[jn] = *(const bf16x8*)&VT[(jn * 16 + col) * 72 + kc];
#pragma unroll
            for (int i = 0; i < 4; ++i)
#pragma unroll
                for (int jn = 0; jn < 4; ++jn)
                    kvacc[i][jn] = __builtin_amdgcn_mfma_f32_16x16x32_bf16(a2[i], b2[jn], kvacc[i][jn], 0, 0, 0);
        }
    }
    const size_t kvbase = (size_t)bh * (kF * kD);
#pragma unroll
    for (int i = 0; i < 4; ++i)
#pragma unroll
        for (int jn = 0; jn < 4; ++jn)
#pragma unroll
            for (int r = 0; r < 4; ++r)
                atomicAdd(&KVg[kvbase + (size_t)(f0 + i * 16 + quad * 4 + r) * kD + jn * 16 + col],
                          kvacc[i][jn][r]);
#pragma unroll
    for (int j = 0; j < 4; ++j) {
        float v = ksum_acc[j];
        v += __shfl_xor(v, 16);
        v += __shfl_xor(v, 32);
        if (quad == 0) atomicAdd(&Ksumg[(size_t)bh * kF + f0 + j * 16 + col], v);
    }
}

// ---------------------------------------------------------------- Phase B (MFMA): attn bf16
// grid (64 bh, 8). Per 64-t tile: S=Q·proj^T (MFMA) -> exp -> Qp[t][f] bf16 (scalar writes);
// denom VALU from own chunk; numer = Qp·KV^T (MFMA, A=Qp rows t, Bt=KVTs rows d).
__global__ __launch_bounds__(256) void phaseB_mfma(const unsigned short* __restrict__ QKVb,
                                                   const unsigned short* __restrict__ projb,
                                                   const unsigned short* __restrict__ KVTb,
                                                   const float* __restrict__ Ksumg,
                                                   unsigned short* __restrict__ attnb) {
    __shared__ unsigned short Qs[64 * 64];      // [t][d]
    __shared__ unsigned short Qp[64 * 264];     // [t][f] pad 8
    __shared__ unsigned short KVTs[64 * 264];   // [d][f] pad 8
    __shared__ float KsS[256];
    __shared__ float denp[4][64];
    const int tid = threadIdx.x, lane = tid & 63, w = tid >> 6;
    const int col = lane & 15, quad = lane >> 4;
    const int bh = blockIdx.x, b = bh >> 4, h = bh & 15;
    const int grp = blockIdx.y;
    const int f0 = w * 64;

    bf16x8 bB[2][4];
#pragma unroll
    for (int s = 0; s < 2; ++s)
#pragma unroll
        for (int j = 0; j < 4; ++j)
            bB[s][j] = *(const bf16x8*)(projb + (size_t)(f0 + j * 16 + col) * 64 + s * 32 + quad * 8);

    // stage KV^T (once) and Ksum
#pragma unroll
    for (int r = 0; r < 8; ++r) {
        int lin = r * 256 + tid;
        int d = lin >> 5, fc8 = (lin & 31) * 8;
        *(bf16x8*)&KVTs[d * 264 + fc8] = *(const bf16x8*)(KVTb + (size_t)bh * 16384 + d * 256 + fc8);
    }
    KsS[tid] = Ksumg[(size_t)bh * kF + tid];

    for (int it = 0; it < 8; ++it) {
        const int tg0 = grp * 512 + it * 64;
        const size_t rowbase = (size_t)(b * kT + tg0) * kQKVs + h * kD;
        __syncthreads();   // protect Qs/Qp/denp reuse (also covers initial KVTs staging)
#pragma unroll
        for (int i2 = 0; i2 < 2; ++i2) {
            int p = (i2 * 4 + w) * 64 + lane;
            gload_lds16(QKVb + rowbase + (size_t)(p >> 3) * kQKVs + (p & 7) * 8,
                        &Qs[(i2 * 4 + w) * 512]);
        }
        __syncthreads();
        bf16x8 av[2][4];
#pragma unroll
        for (int s = 0; s < 2; ++s)
#pragma unroll
            for (int i = 0; i < 4; ++i)
                av[s][i] = *(const bf16x8*)&Qs[(i * 16 + col) * 64 + s * 32 + quad * 8];
#pragma unroll
        for (int j = 0; j < 4; ++j) {
            f32x4 sa[4];
#pragma unroll
            for (int i = 0; i < 4; ++i) sa[i] = (f32x4){0.f, 0.f, 0.f, 0.f};
#pragma unroll
            for (int s = 0; s < 2; ++s)
#pragma unroll
                for (int i = 0; i < 4; ++i)
                    sa[i] = __builtin_amdgcn_mfma_f32_16x16x32_bf16(av[s][i], bB[s][j], sa[i], 0, 0, 0);
            const int f = f0 + j * 16 + col;
#pragma unroll
            for (int i = 0; i < 4; ++i) {
                const int tb = i * 16 + quad * 4;
                Qp[(tb + 0) * 264 + f] = f2bf(__expf(sa[i][0]) + 1e-6f);
                Qp[(tb + 1) * 264 + f] = f2bf(__expf(sa[i][1]) + 1e-6f);
                Qp[(tb + 2) * 264 + f] = f2bf(__expf(sa[i][2]) + 1e-6f);
                Qp[(tb + 3) * 264 + f] = f2bf(__expf(sa[i][3]) + 1e-6f);
            }
        }
        // denom partial over own f-chunk (wave-local rows/cols)
        float dp = 0.f;
#pragma unroll
        for (int u = 0; u < 64; u += 8) {
            bf16x8 qv = *(const bf16x8*)&Qp[lane * 264 + f0 + u];
#pragma unroll
            for (int k2 = 0; k2 < 8; ++k2)
                dp += bf2f((unsigned short)qv[k2]) * KsS[f0 + u + k2];
        }
        denp[w][lane] = dp;
        __syncthreads();   // Qp (all chunks) + denp ready
        f32x4 nacc[4];
#pragma unroll
        for (int jn = 0; jn < 4; ++jn) nacc[jn] = (f32x4){0.f, 0.f, 0.f, 0.f};
#pragma unroll
        for (int s = 0; s < 8; ++s) {
            const int kc = s * 32 + quad * 8;
            bf16x8 aq = *(const bf16x8*)&Qp[(w * 16 + col) * 264 + kc];
#pragma unroll
            for (int jn = 0; jn < 4; ++jn) {
                bf16x8 bk = *(const bf16x8*)&KVTs[(jn * 16 + col) * 264 + kc];
                nacc[jn] = __builtin_amdgcn_mfma_f32_16x16x32_bf16(aq, bk, nacc[jn], 0, 0, 0);
            }
        }
#pragma unroll
        for (int r = 0; r < 4; ++r) {
            const int tl = w * 16 + quad * 4 + r;
            float den = denp[0][tl] + denp[1][tl] + denp[2][tl] + denp[3][tl];
            float rd = 1.f / fmaxf(den, 1e-6f);
            const size_t ob = (size_t)(b * kT + tg0 + tl) * kE + h * kD;
#pragma unroll
            for (int jn = 0; jn < 4; ++jn)
                attnb[ob + jn * 16 + col] = f2bf(nacc[jn][r] * rd);
        }
    }
}

// ---------------------------------------------------------------- launch
extern "C" void kernel_launch(void* const* d_in, const int* in_sizes, int n_in,
                              void* d_out, int out_size, void* d_ws, size_t ws_size,
                              hipStream_t stream) {
    (void)in_sizes; (void)n_in; (void)out_size; (void)ws_size;
    const float* x    = (const float*)d_in[0];
    const float* Wq   = (const float*)d_in[1];
    const float* Wk   = (const float*)d_in[2];
    const float* Wv   = (const float*)d_in[3];
    const float* Wo   = (const float*)d_in[4];
    const float* proj = (const float*)d_in[5];
    float* out = (float*)d_out;

    char* ws = (char*)d_ws;
    unsigned short* QKVb  = (unsigned short*)(ws);               // 96MB
    float*          C2    = (float*)(ws);                        // aliases QKVb (post-phaseB)
    unsigned short* attnb = (unsigned short*)(ws + 100663296);   // 32MB
    unsigned short* Abuf  = (unsigned short*)(ws + 100663296);   // aliases attnb (pre-gemm1)
    unsigned short* Btqkv = (unsigned short*)(ws + 134217728);   // 3MB
    unsigned short* WoT   = (unsigned short*)(ws + 137363456);   // 2MB
    unsigned short* projb = (unsigned short*)(ws + 139460608);   // 32KB
    float*          KVg   = (float*)(ws + 139493376);            // 4MB
    float*          Ksumg = (float*)(ws + 143687680);            // 64KB (contiguous after KVg)
    unsigned short* KVTb  = (unsigned short*)(ws + 143753216);   // 2MB

    copy_x_kernel<<<dim3(8192), 256, 0, stream>>>(x, out);

    trans_f2b_kernel<<<dim3(64, 8, 4), 256, 0, stream>>>(x, Abuf, kIn, kT,
                                                         (long)kIn * kT, (long)kT * kIn);
    trans_f2b_kernel<<<dim3(16, 8, 1), 256, 0, stream>>>(Wq, Btqkv, kIn, kE, 0, 0);
    trans_f2b_kernel<<<dim3(16, 8, 1), 256, 0, stream>>>(Wk, Btqkv + (size_t)kE * kIn, kIn, kE, 0, 0);
    trans_f2b_kernel<<<dim3(16, 8, 1), 256, 0, stream>>>(Wv, Btqkv + (size_t)2 * kE * kIn, kIn, kE, 0, 0);
    trans_f2b_kernel<<<dim3(16, 16, 1), 256, 0, stream>>>(Wo, WoT, kE, kE, 0, 0);
    f2b_flat_kernel<<<dim3(16), 256, 0, stream>>>(proj, projb, kF * kD / 4);

    gemm_mfma_b16<<<dim3(24, 128), 256, 0, stream>>>(Abuf, Btqkv, QKVb, kQKVs, kIn);

    const int nz = kB * kH * kF * kD + kB * kH * kF;
    zero_kernel<<<dim3((nz + 255) / 256), 256, 0, stream>>>(KVg, nz);

    phaseA_mfma<<<dim3(64, 8), 256, 0, stream>>>(QKVb, projb, KVg, Ksumg);
    // KV fp32 [bh][f][d] -> KVT bf16 [bh][d][f]
    trans_f2b_kernel<<<dim3(1, 4, 64), 256, 0, stream>>>(KVg, KVTb, kF, kD,
                                                         (long)kF * kD, (long)kF * kD);
    phaseB_mfma<<<dim3(64, 8), 256, 0, stream>>>(QKVb, projb, KVTb, Ksumg, attnb);

    gemm_mfma_f32<<<dim3(8, 128), 256, 0, stream>>>(attnb, WoT, C2, kE, kE);
    out_transpose_kernel<<<dim3(64, 64), 256, 0, stream>>>(C2, out);
}

// Round 4
// 381.018 us; speedup vs baseline: 4.6055x; 1.0891x over previous
//
#include <hip/hip_runtime.h>

// PerformerAttnBlock — Round 4: LDS XOR-swizzle (kill 16-way bank conflicts),
// LDS-repack epilogues, gemm2 fused transposed store (out_transpose deleted).
// B=4, IN=512, T=4096, EMBED=1024, H=16, D=64, F=256.
// WS (bytes):
//   0         QKVb bf16 [16384][3072] (96MB)
//   100663296 attnb bf16 [16384][1024] (32MB)  -- Abuf bf16 [16384][512] aliases pre-gemm1
//   134217728 Btqkv bf16 [3072][512] (3MB)
//   137363456 WoT bf16 [1024][1024] (2MB)
//   139460608 projb bf16 [256][64] (32KB)
//   139493376 KVg fp32 [64][256][64] (4MB)
//   143687680 Ksumg fp32 [64][256] (64KB)
//   143753216 KVTb bf16 [64][64][256] (2MB)

constexpr int kB  = 4;
constexpr int kIn = 512;
constexpr int kT  = 4096;
constexpr int kE  = 1024;
constexpr int kH  = 16;
constexpr int kD  = 64;
constexpr int kF  = 256;
constexpr int kQKVs = 3072;

typedef __attribute__((ext_vector_type(8))) short bf16x8;
typedef __attribute__((ext_vector_type(4))) float f32x4;

__device__ __forceinline__ unsigned short f2bf(float f) {
    unsigned u = __float_as_uint(f);
    u += 0x7fff + ((u >> 16) & 1);          // RNE
    return (unsigned short)(u >> 16);
}
__device__ __forceinline__ float bf2f(unsigned short s) {
    return __uint_as_float(((unsigned)s) << 16);
}
__device__ __forceinline__ void gload_lds16(const void* g, void* l) {
    __builtin_amdgcn_global_load_lds((const __attribute__((address_space(1))) void*)g,
                                     (__attribute__((address_space(3))) void*)l, 16, 0, 0);
}

// ---------------------------------------------------------------- zero
__global__ __launch_bounds__(256) void zero_kernel(float* __restrict__ p, int n) {
    int i = blockIdx.x * 256 + threadIdx.x;
    if (i < n) p[i] = 0.f;
}

// ---------------------------------------------------------------- copy x -> out[:, :512, :]
__global__ __launch_bounds__(256) void copy_x_kernel(const float* __restrict__ x,
                                                     float* __restrict__ out) {
    const int perB4 = kIn * kT / 4;
    int idx = blockIdx.x * 256 + threadIdx.x;
    if (idx < kB * perB4) {
        int b = idx / perB4, e = idx % perB4;
        ((float4*)out)[(size_t)b * ((kIn + kE) * kT / 4) + e] = ((const float4*)x)[idx];
    }
}

// ---------------------------------------------------------------- flat fp32->bf16
__global__ __launch_bounds__(256) void f2b_flat_kernel(const float* __restrict__ s,
                                                       unsigned short* __restrict__ d, int n4) {
    int i = blockIdx.x * 256 + threadIdx.x;
    if (i < n4) {
        float4 v = ((const float4*)s)[i];
        ushort4 o;
        o.x = f2bf(v.x); o.y = f2bf(v.y); o.z = f2bf(v.z); o.w = f2bf(v.w);
        ((ushort4*)d)[i] = o;
    }
}

// ---------------------------------------------------------------- transpose + fp32->bf16
// src [R][C] fp32 (+z*sstride), dst [C][R] bf16 (+z*dstride)
__global__ __launch_bounds__(256) void trans_f2b_kernel(const float* __restrict__ src,
                                                        unsigned short* __restrict__ dst,
                                                        int R, int C,
                                                        long sstride, long dstride) {
    __shared__ float L[64][68];
    src += (size_t)blockIdx.z * sstride;
    dst += (size_t)blockIdx.z * dstride;
    const int c0 = blockIdx.x * 64, r0 = blockIdx.y * 64;
    const int tid = threadIdx.x;
#pragma unroll
    for (int it = 0; it < 4; ++it) {
        int lin = it * 256 + tid;
        int i = lin >> 4;
        int j4 = (lin & 15) * 4;
        float4 v = *(const float4*)(src + (size_t)(r0 + i) * C + c0 + j4);
        L[j4 + 0][i] = v.x; L[j4 + 1][i] = v.y; L[j4 + 2][i] = v.z; L[j4 + 3][i] = v.w;
    }
    __syncthreads();
#pragma unroll
    for (int it = 0; it < 4; ++it) {
        int lin = it * 256 + tid;
        int cc = lin >> 4;
        int r4 = (lin & 15) * 4;
        ushort4 o;
        o.x = f2bf(L[cc][r4 + 0]); o.y = f2bf(L[cc][r4 + 1]);
        o.z = f2bf(L[cc][r4 + 2]); o.w = f2bf(L[cc][r4 + 3]);
        *(ushort4*)(dst + (size_t)(c0 + cc) * R + r0 + r4) = o;
    }
}

// ---------------------------------------------------------------- fused Wq/Wk/Wv transpose
__global__ __launch_bounds__(256) void trans_qkv_kernel(const float* __restrict__ Wq,
                                                        const float* __restrict__ Wk,
                                                        const float* __restrict__ Wv,
                                                        unsigned short* __restrict__ dst) {
    __shared__ float L[64][68];
    const int z = blockIdx.z;
    const float* src = (z == 0) ? Wq : (z == 1) ? Wk : Wv;
    dst += (size_t)z * kE * kIn;
    const int c0 = blockIdx.x * 64, r0 = blockIdx.y * 64;   // c over E, r over In
    const int tid = threadIdx.x;
#pragma unroll
    for (int it = 0; it < 4; ++it) {
        int lin = it * 256 + tid;
        int i = lin >> 4;
        int j4 = (lin & 15) * 4;
        float4 v = *(const float4*)(src + (size_t)(r0 + i) * kE + c0 + j4);
        L[j4 + 0][i] = v.x; L[j4 + 1][i] = v.y; L[j4 + 2][i] = v.z; L[j4 + 3][i] = v.w;
    }
    __syncthreads();
#pragma unroll
    for (int it = 0; it < 4; ++it) {
        int lin = it * 256 + tid;
        int cc = lin >> 4;
        int r4 = (lin & 15) * 4;
        ushort4 o;
        o.x = f2bf(L[cc][r4 + 0]); o.y = f2bf(L[cc][r4 + 1]);
        o.z = f2bf(L[cc][r4 + 2]); o.w = f2bf(L[cc][r4 + 3]);
        *(ushort4*)(dst + (size_t)(c0 + cc) * kIn + r0 + r4) = o;
    }
}

// ---------------------------------------------------------------- GEMM1: bf16 out, XOR-swizzled LDS
// A [M][K], Bt [N][K] bf16; C [M][N] bf16. 128x128 tile, BK=64, 4 waves of 64x64.
__global__ __launch_bounds__(256) void gemm_mfma_b16(const unsigned short* __restrict__ A,
                                                     const unsigned short* __restrict__ Bt,
                                                     unsigned short* __restrict__ C,
                                                     int N, int K) {
    __shared__ unsigned short As[128 * 64];
    __shared__ unsigned short Bs[128 * 64];
    __shared__ float Tt[4][16 * 20];      // per-wave 16(t) x 16(n) repack, stride 20
    const int tid = threadIdx.x;
    const int lane = tid & 63, w = tid >> 6;
    const int col = lane & 15, quad = lane >> 4;
    const int n0 = blockIdx.x * 128, m0 = blockIdx.y * 128;
    const int wm = (w >> 1) * 64, wn = (w & 1) * 64;
    f32x4 acc[4][4];
#pragma unroll
    for (int i = 0; i < 4; ++i)
#pragma unroll
        for (int j = 0; j < 4; ++j) acc[i][j] = (f32x4){0.f, 0.f, 0.f, 0.f};

    const int swz = col & 7;                       // read-side XOR key (row&7 == col&7)
    for (int k0 = 0; k0 < K; k0 += 64) {
        __syncthreads();
#pragma unroll
        for (int i = 0; i < 4; ++i) {
            int p = (i * 4 + w) * 64 + lane;
            int row = p >> 3;
            int cg = ((p & 7) ^ (row & 7)) * 8;    // swizzled global chunk
            gload_lds16(A + (size_t)(m0 + row) * K + k0 + cg, &As[(i * 4 + w) * 512]);
            gload_lds16(Bt + (size_t)(n0 + row) * K + k0 + cg, &Bs[(i * 4 + w) * 512]);
        }
        __syncthreads();
#pragma unroll
        for (int s = 0; s < 2; ++s) {
            const int kc = ((s * 4 + quad) ^ swz) * 8;
            bf16x8 av[4], bv[4];
#pragma unroll
            for (int i = 0; i < 4; ++i)
                av[i] = *(const bf16x8*)&As[(wm + i * 16 + col) * 64 + kc];
#pragma unroll
            for (int j = 0; j < 4; ++j)
                bv[j] = *(const bf16x8*)&Bs[(wn + j * 16 + col) * 64 + kc];
#pragma unroll
            for (int i = 0; i < 4; ++i)
#pragma unroll
                for (int j = 0; j < 4; ++j)
                    acc[i][j] = __builtin_amdgcn_mfma_f32_16x16x32_bf16(av[i], bv[j], acc[i][j], 0, 0, 0);
        }
    }
    // epilogue: per-wave LDS repack -> ushort4 stores ([m][n] row-major)
    const int t2 = lane >> 2, n4 = (lane & 3) * 4;
#pragma unroll
    for (int i = 0; i < 4; ++i)
#pragma unroll
        for (int j = 0; j < 4; ++j) {
#pragma unroll
            for (int r = 0; r < 4; ++r)
                Tt[w][(quad * 4 + r) * 20 + col] = acc[i][j][r];
            float4 v = *(const float4*)&Tt[w][t2 * 20 + n4];
            ushort4 o;
            o.x = f2bf(v.x); o.y = f2bf(v.y); o.z = f2bf(v.z); o.w = f2bf(v.w);
            *(ushort4*)(C + (size_t)(m0 + wm + i * 16 + t2) * N + n0 + wn + j * 16 + n4) = o;
        }
}

// ---------------------------------------------------------------- GEMM2: attn @ Wo, direct
// transposed fp32 store into out[b][512+n][t]. A [M=16384][K=1024], Bt [N=1024][K].
__global__ __launch_bounds__(256) void gemm_mfma_out(const unsigned short* __restrict__ A,
                                                     const unsigned short* __restrict__ Bt,
                                                     float* __restrict__ out,
                                                     int N, int K) {
    __shared__ unsigned short As[128 * 64];
    __shared__ unsigned short Bs[128 * 64];
    __shared__ float Tt[4][16 * 20];      // per-wave 16(n) x 16(t) repack, stride 20
    const int tid = threadIdx.x;
    const int lane = tid & 63, w = tid >> 6;
    const int col = lane & 15, quad = lane >> 4;
    const int n0 = blockIdx.x * 128, m0 = blockIdx.y * 128;
    const int wm = (w >> 1) * 64, wn = (w & 1) * 64;
    f32x4 acc[4][4];
#pragma unroll
    for (int i = 0; i < 4; ++i)
#pragma unroll
        for (int j = 0; j < 4; ++j) acc[i][j] = (f32x4){0.f, 0.f, 0.f, 0.f};

    const int swz = col & 7;
    for (int k0 = 0; k0 < K; k0 += 64) {
        __syncthreads();
#pragma unroll
        for (int i = 0; i < 4; ++i) {
            int p = (i * 4 + w) * 64 + lane;
            int row = p >> 3;
            int cg = ((p & 7) ^ (row & 7)) * 8;
            gload_lds16(A + (size_t)(m0 + row) * K + k0 + cg, &As[(i * 4 + w) * 512]);
            gload_lds16(Bt + (size_t)(n0 + row) * K + k0 + cg, &Bs[(i * 4 + w) * 512]);
        }
        __syncthreads();
#pragma unroll
        for (int s = 0; s < 2; ++s) {
            const int kc = ((s * 4 + quad) ^ swz) * 8;
            bf16x8 av[4], bv[4];
#pragma unroll
            for (int i = 0; i < 4; ++i)
                av[i] = *(const bf16x8*)&As[(wm + i * 16 + col) * 64 + kc];
#pragma unroll
            for (int j = 0; j < 4; ++j)
                bv[j] = *(const bf16x8*)&Bs[(wn + j * 16 + col) * 64 + kc];
#pragma unroll
            for (int i = 0; i < 4; ++i)
#pragma unroll
                for (int j = 0; j < 4; ++j)
                    acc[i][j] = __builtin_amdgcn_mfma_f32_16x16x32_bf16(av[i], bv[j], acc[i][j], 0, 0, 0);
        }
    }
    // epilogue: transpose per 16x16 fragment in per-wave LDS, store out[n][t] coalesced
    const int b = m0 >> 12, t0 = m0 & 4095;
    float* dst = out + (size_t)b * (kIn + kE) * kT + (size_t)kIn * kT;
    const int n2 = lane >> 2, t4 = (lane & 3) * 4;
#pragma unroll
    for (int i = 0; i < 4; ++i)
#pragma unroll
        for (int j = 0; j < 4; ++j) {
            *(float4*)&Tt[w][col * 20 + quad * 4] =
                (float4){acc[i][j][0], acc[i][j][1], acc[i][j][2], acc[i][j][3]};
            float4 v = *(const float4*)&Tt[w][n2 * 20 + t4];
            *(float4*)(dst + (size_t)(n0 + wn + j * 16 + n2) * kT + t0 + wm + i * 16 + t4) = v;
        }
}

// ---------------------------------------------------------------- Phase A (MFMA): KV, Ksum
__global__ __launch_bounds__(256) void phaseA_mfma(const unsigned short* __restrict__ QKVb,
                                                   const unsigned short* __restrict__ projb,
                                                   float* __restrict__ KVg,
                                                   float* __restrict__ Ksumg) {
    __shared__ unsigned short Ks[64 * 64];     // [t][d] XOR-swizzled chunks
    __shared__ unsigned short VT[64 * 72];     // [d][t] pad 8
    __shared__ unsigned short KpT[256 * 72];   // [f][t] pad 8
    const int tid = threadIdx.x, lane = tid & 63, w = tid >> 6;
    const int col = lane & 15, quad = lane >> 4;
    const int bh = blockIdx.x, b = bh >> 4, h = bh & 15;
    const int grp = blockIdx.y;
    const int f0 = w * 64;
    const int swz = col & 7;

    bf16x8 bB[2][4];   // proj B-fragments, invariant
#pragma unroll
    for (int s = 0; s < 2; ++s)
#pragma unroll
        for (int j = 0; j < 4; ++j)
            bB[s][j] = *(const bf16x8*)(projb + (size_t)(f0 + j * 16 + col) * 64 + s * 32 + quad * 8);

    f32x4 kvacc[4][4];
#pragma unroll
    for (int i = 0; i < 4; ++i)
#pragma unroll
        for (int j = 0; j < 4; ++j) kvacc[i][j] = (f32x4){0.f, 0.f, 0.f, 0.f};
    float ksum_acc[4] = {0.f, 0.f, 0.f, 0.f};

    for (int it = 0; it < 8; ++it) {
        const size_t rowbase = (size_t)(b * kT + grp * 512 + it * 64) * kQKVs + h * kD;
        __syncthreads();
#pragma unroll
        for (int i2 = 0; i2 < 2; ++i2) {
            int p = (i2 * 4 + w) * 64 + lane;
            int row = p >> 3;
            int cg = ((p & 7) ^ (row & 7)) * 8;
            gload_lds16(QKVb + rowbase + 1024 + (size_t)row * kQKVs + cg, &Ks[(i2 * 4 + w) * 512]);
        }
#pragma unroll
        for (int r = 0; r < 4; ++r) {
            int lin = r * 256 + tid;
            int t = lin >> 4, d4 = (lin & 15) * 4;
            ushort4 v = *(const ushort4*)(QKVb + rowbase + 2048 + (size_t)t * kQKVs + d4);
            VT[(d4 + 0) * 72 + t] = v.x; VT[(d4 + 1) * 72 + t] = v.y;
            VT[(d4 + 2) * 72 + t] = v.z; VT[(d4 + 3) * 72 + t] = v.w;
        }
        __syncthreads();
        bf16x8 av[2][4];
#pragma unroll
        for (int s = 0; s < 2; ++s)
#pragma unroll
            for (int i = 0; i < 4; ++i)
                av[s][i] = *(const bf16x8*)&Ks[(i * 16 + col) * 64 + ((s * 4 + quad) ^ swz) * 8];
#pragma unroll
        for (int j = 0; j < 4; ++j) {
            f32x4 sa[4];
#pragma unroll
            for (int i = 0; i < 4; ++i) sa[i] = (f32x4){0.f, 0.f, 0.f, 0.f};
#pragma unroll
            for (int s = 0; s < 2; ++s)
#pragma unroll
                for (int i = 0; i < 4; ++i)
                    sa[i] = __builtin_amdgcn_mfma_f32_16x16x32_bf16(av[s][i], bB[s][j], sa[i], 0, 0, 0);
            const int f = f0 + j * 16 + col;
#pragma unroll
            for (int i = 0; i < 4; ++i) {
                float e0 = __expf(sa[i][0]) + 1e-6f;
                float e1 = __expf(sa[i][1]) + 1e-6f;
                float e2 = __expf(sa[i][2]) + 1e-6f;
                float e3 = __expf(sa[i][3]) + 1e-6f;
                ksum_acc[j] += (e0 + e1) + (e2 + e3);
                ushort4 pk;
                pk.x = f2bf(e0); pk.y = f2bf(e1); pk.z = f2bf(e2); pk.w = f2bf(e3);
                *(ushort4*)&KpT[f * 72 + i * 16 + quad * 4] = pk;
            }
        }
#pragma unroll
        for (int s = 0; s < 2; ++s) {
            const int kc = s * 32 + quad * 8;
            bf16x8 a2[4], b2[4];
#pragma unroll
            for (int i = 0; i < 4; ++i)
                a2[i] = *(const bf16x8*)&KpT[(f0 + i * 16 + col) * 72 + kc];
#pragma unroll
            for (int jn = 0; jn < 4; ++jn)
                b2[jn] = *(const bf16x8*)&VT[(jn * 16 + col) * 72 + kc];
#pragma unroll
            for (int i = 0; i < 4; ++i)
#pragma unroll
                for (int jn = 0; jn < 4; ++jn)
                    kvacc[i][jn] = __builtin_amdgcn_mfma_f32_16x16x32_bf16(a2[i], b2[jn], kvacc[i][jn], 0, 0, 0);
        }
    }
    const size_t kvbase = (size_t)bh * (kF * kD);
#pragma unroll
    for (int i = 0; i < 4; ++i)
#pragma unroll
        for (int jn = 0; jn < 4; ++jn)
#pragma unroll
            for (int r = 0; r < 4; ++r)
                atomicAdd(&KVg[kvbase + (size_t)(f0 + i * 16 + quad * 4 + r) * kD + jn * 16 + col],
                          kvacc[i][jn][r]);
#pragma unroll
    for (int j = 0; j < 4; ++j) {
        float v = ksum_acc[j];
        v += __shfl_xor(v, 16);
        v += __shfl_xor(v, 32);
        if (quad == 0) atomicAdd(&Ksumg[(size_t)bh * kF + f0 + j * 16 + col], v);
    }
}

// ---------------------------------------------------------------- Phase B (MFMA): attn bf16
__global__ __launch_bounds__(256) void phaseB_mfma(const unsigned short* __restrict__ QKVb,
                                                   const unsigned short* __restrict__ projb,
                                                   const unsigned short* __restrict__ KVTb,
                                                   const float* __restrict__ Ksumg,
                                                   unsigned short* __restrict__ attnb) {
    __shared__ unsigned short Qs[64 * 64];      // [t][d] XOR-swizzled chunks
    __shared__ unsigned short Qp[64 * 264];     // [t][f] pad 8
    __shared__ unsigned short KVTs[64 * 264];   // [d][f] pad 8
    __shared__ float KsS[256];
    __shared__ float denp[4][64];
    const int tid = threadIdx.x, lane = tid & 63, w = tid >> 6;
    const int col = lane & 15, quad = lane >> 4;
    const int bh = blockIdx.x, b = bh >> 4, h = bh & 15;
    const int grp = blockIdx.y;
    const int f0 = w * 64;
    const int swz = col & 7;

    bf16x8 bB[2][4];
#pragma unroll
    for (int s = 0; s < 2; ++s)
#pragma unroll
        for (int j = 0; j < 4; ++j)
            bB[s][j] = *(const bf16x8*)(projb + (size_t)(f0 + j * 16 + col) * 64 + s * 32 + quad * 8);

#pragma unroll
    for (int r = 0; r < 8; ++r) {
        int lin = r * 256 + tid;
        int d = lin >> 5, fc8 = (lin & 31) * 8;
        *(bf16x8*)&KVTs[d * 264 + fc8] = *(const bf16x8*)(KVTb + (size_t)bh * 16384 + d * 256 + fc8);
    }
    KsS[tid] = Ksumg[(size_t)bh * kF + tid];

    for (int it = 0; it < 8; ++it) {
        const int tg0 = grp * 512 + it * 64;
        const size_t rowbase = (size_t)(b * kT + tg0) * kQKVs + h * kD;
        __syncthreads();
#pragma unroll
        for (int i2 = 0; i2 < 2; ++i2) {
            int p = (i2 * 4 + w) * 64 + lane;
            int row = p >> 3;
            int cg = ((p & 7) ^ (row & 7)) * 8;
            gload_lds16(QKVb + rowbase + (size_t)row * kQKVs + cg, &Qs[(i2 * 4 + w) * 512]);
        }
        __syncthreads();
        bf16x8 av[2][4];
#pragma unroll
        for (int s = 0; s < 2; ++s)
#pragma unroll
            for (int i = 0; i < 4; ++i)
                av[s][i] = *(const bf16x8*)&Qs[(i * 16 + col) * 64 + ((s * 4 + quad) ^ swz) * 8];
#pragma unroll
        for (int j = 0; j < 4; ++j) {
            f32x4 sa[4];
#pragma unroll
            for (int i = 0; i < 4; ++i) sa[i] = (f32x4){0.f, 0.f, 0.f, 0.f};
#pragma unroll
            for (int s = 0; s < 2; ++s)
#pragma unroll
                for (int i = 0; i < 4; ++i)
                    sa[i] = __builtin_amdgcn_mfma_f32_16x16x32_bf16(av[s][i], bB[s][j], sa[i], 0, 0, 0);
            const int f = f0 + j * 16 + col;
#pragma unroll
            for (int i = 0; i < 4; ++i) {
                const int tb = i * 16 + quad * 4;
                Qp[(tb + 0) * 264 + f] = f2bf(__expf(sa[i][0]) + 1e-6f);
                Qp[(tb + 1) * 264 + f] = f2bf(__expf(sa[i][1]) + 1e-6f);
                Qp[(tb + 2) * 264 + f] = f2bf(__expf(sa[i][2]) + 1e-6f);
                Qp[(tb + 3) * 264 + f] = f2bf(__expf(sa[i][3]) + 1e-6f);
            }
        }
        float dp = 0.f;
#pragma unroll
        for (int u = 0; u < 64; u += 8) {
            bf16x8 qv = *(const bf16x8*)&Qp[lane * 264 + f0 + u];
#pragma unroll
            for (int k2 = 0; k2 < 8; ++k2)
                dp += bf2f((unsigned short)qv[k2]) * KsS[f0 + u + k2];
        }
        denp[w][lane] = dp;
        __syncthreads();
        f32x4 nacc[4];
#pragma unroll
        for (int jn = 0; jn < 4; ++jn) nacc[jn] = (f32x4){0.f, 0.f, 0.f, 0.f};
#pragma unroll
        for (int s = 0; s < 8; ++s) {
            const int kc = s * 32 + quad * 8;
            bf16x8 aq = *(const bf16x8*)&Qp[(w * 16 + col) * 264 + kc];
#pragma unroll
            for (int jn = 0; jn < 4; ++jn) {
                bf16x8 bk = *(const bf16x8*)&KVTs[(jn * 16 + col) * 264 + kc];
                nacc[jn] = __builtin_amdgcn_mfma_f32_16x16x32_bf16(aq, bk, nacc[jn], 0, 0, 0);
            }
        }
#pragma unroll
        for (int r = 0; r < 4; ++r) {
            const int tl = w * 16 + quad * 4 + r;
            float den = denp[0][tl] + denp[1][tl] + denp[2][tl] + denp[3][tl];
            float rd = 1.f / fmaxf(den, 1e-6f);
            const size_t ob = (size_t)(b * kT + tg0 + tl) * kE + h * kD;
#pragma unroll
            for (int jn = 0; jn < 4; ++jn)
                attnb[ob + jn * 16 + col] = f2bf(nacc[jn][r] * rd);
        }
    }
}

// ---------------------------------------------------------------- launch
extern "C" void kernel_launch(void* const* d_in, const int* in_sizes, int n_in,
                              void* d_out, int out_size, void* d_ws, size_t ws_size,
                              hipStream_t stream) {
    (void)in_sizes; (void)n_in; (void)out_size; (void)ws_size;
    const float* x    = (const float*)d_in[0];
    const float* Wq   = (const float*)d_in[1];
    const float* Wk   = (const float*)d_in[2];
    const float* Wv   = (const float*)d_in[3];
    const float* Wo   = (const float*)d_in[4];
    const float* proj = (const float*)d_in[5];
    float* out = (float*)d_out;

    char* ws = (char*)d_ws;
    unsigned short* QKVb  = (unsigned short*)(ws);               // 96MB
    unsigned short* attnb = (unsigned short*)(ws + 100663296);   // 32MB
    unsigned short* Abuf  = (unsigned short*)(ws + 100663296);   // aliases attnb (pre-gemm1)
    unsigned short* Btqkv = (unsigned short*)(ws + 134217728);   // 3MB
    unsigned short* WoT   = (unsigned short*)(ws + 137363456);   // 2MB
    unsigned short* projb = (unsigned short*)(ws + 139460608);   // 32KB
    float*          KVg   = (float*)(ws + 139493376);            // 4MB
    float*          Ksumg = (float*)(ws + 143687680);            // 64KB
    unsigned short* KVTb  = (unsigned short*)(ws + 143753216);   // 2MB

    copy_x_kernel<<<dim3(8192), 256, 0, stream>>>(x, out);

    trans_f2b_kernel<<<dim3(64, 8, 4), 256, 0, stream>>>(x, Abuf, kIn, kT,
                                                         (long)kIn * kT, (long)kT * kIn);
    trans_qkv_kernel<<<dim3(16, 8, 3), 256, 0, stream>>>(Wq, Wk, Wv, Btqkv);
    trans_f2b_kernel<<<dim3(16, 16, 1), 256, 0, stream>>>(Wo, WoT, kE, kE, 0, 0);
    f2b_flat_kernel<<<dim3(16), 256, 0, stream>>>(proj, projb, kF * kD / 4);

    gemm_mfma_b16<<<dim3(24, 128), 256, 0, stream>>>(Abuf, Btqkv, QKVb, kQKVs, kIn);

    const int nz = kB * kH * kF * kD + kB * kH * kF;
    zero_kernel<<<dim3((nz + 255) / 256), 256, 0, stream>>>(KVg, nz);

    phaseA_mfma<<<dim3(64, 8), 256, 0, stream>>>(QKVb, projb, KVg, Ksumg);
    trans_f2b_kernel<<<dim3(1, 4, 64), 256, 0, stream>>>(KVg, KVTb, kF, kD,
                                                         (long)kF * kD, (long)kF * kD);
    phaseB_mfma<<<dim3(64, 8), 256, 0, stream>>>(QKVb, projb, KVTb, Ksumg, attnb);

    gemm_mfma_out<<<dim3(8, 128), 256, 0, stream>>>(attnb, WoT, out, kE, kE);
}